// Round 1
// baseline (829.574 us; speedup 1.0000x reference)
//
#include <hip/hip_runtime.h>
#include <math.h>

#define PI_F 3.14159265358979323846f

// ---------------- binning (counting sort by dst) ----------------

__global__ void count_kernel(const int* __restrict__ dst, int* __restrict__ cnt, int E) {
    int e = blockIdx.x * 256 + threadIdx.x;
    if (e < E) atomicAdd(&cnt[dst[e]], 1);
}

// single block, 1024 threads: exclusive prefix sum of cnt[0..n) -> offs, and
// cnt becomes the running cursor (initialized to offs) for the fill pass.
__global__ void scan_kernel(int* __restrict__ cntcur, int* __restrict__ offs, int n, int total) {
    __shared__ int sdata[1024];
    int tid = threadIdx.x;
    int chunk = (n + 1023) >> 10;
    int base = tid * chunk;
    int sum = 0;
    for (int i = 0; i < chunk; i++) {
        int idx = base + i;
        if (idx < n) sum += cntcur[idx];
    }
    sdata[tid] = sum;
    __syncthreads();
    for (int off = 1; off < 1024; off <<= 1) {
        int v = (tid >= off) ? sdata[tid - off] : 0;
        __syncthreads();
        sdata[tid] += v;
        __syncthreads();
    }
    int run = (tid == 0) ? 0 : sdata[tid - 1];
    for (int i = 0; i < chunk; i++) {
        int idx = base + i;
        if (idx >= n) break;
        int c = cntcur[idx];
        offs[idx] = run;
        cntcur[idx] = run;  // cursor copy
        run += c;
    }
    if (tid == 0) offs[n] = total;
}

// scatter edges into dst-bins; compute fourier basis once, into bin order.
// basis per dim: [1, sin(pi x), cos(pi x), sin(2 pi x)]
__global__ void fill_kernel(const int* __restrict__ src, const int* __restrict__ dst,
                            const float* __restrict__ el, int* __restrict__ cursor,
                            int* __restrict__ srcS, float* __restrict__ basisS, int E) {
    int e = blockIdx.x * 256 + threadIdx.x;
    if (e >= E) return;
    int d = dst[e];
    int pos = atomicAdd(&cursor[d], 1);
    srcS[pos] = src[e];
    float2 xy = *(const float2*)(el + 2 * (size_t)e);
    float4 b0, b1;
    b0.x = 1.0f; b0.y = __sinf(PI_F * xy.x); b0.z = __cosf(PI_F * xy.x); b0.w = __sinf(2.0f * PI_F * xy.x);
    b1.x = 1.0f; b1.y = __sinf(PI_F * xy.y); b1.z = __cosf(PI_F * xy.y); b1.w = __sinf(2.0f * PI_F * xy.y);
    float4* bp = (float4*)(basisS + (size_t)pos * 8);
    bp[0] = b0;
    bp[1] = b1;
}

// ---------------- per-layer: edge aggregation into A[n, 8*F] ----------------
// one wave per dst node; lane -> feature f (F=64) or (f, edge-slot) (F=16).
// A[n][b*F + f] = sum over incoming edges of basis[e][b] * h[src][f]

template <int F>
__global__ __launch_bounds__(256) void agg_kernel(const float* __restrict__ h,
                                                  const int* __restrict__ srcS,
                                                  const float* __restrict__ basisS,
                                                  const int* __restrict__ offs,
                                                  float* __restrict__ A, int nN) {
    constexpr int SLOTS = 64 / F;
    int wid = (blockIdx.x * 256 + threadIdx.x) >> 6;
    int lane = threadIdx.x & 63;
    if (wid >= nN) return;
    int f = lane & (F - 1);
    int slot = lane / F;
    int start = offs[wid], end = offs[wid + 1];
    float a0 = 0, a1 = 0, a2 = 0, a3 = 0, a4 = 0, a5 = 0, a6 = 0, a7 = 0;
    for (int j = start + slot; j < end; j += SLOTS) {
        int s = srcS[j];
        float hv = h[(size_t)s * F + f];
        const float4* bp = (const float4*)(basisS + (size_t)j * 8);
        float4 b0 = bp[0];
        float4 b1 = bp[1];
        a0 += b0.x * hv; a1 += b0.y * hv; a2 += b0.z * hv; a3 += b0.w * hv;
        a4 += b1.x * hv; a5 += b1.y * hv; a6 += b1.z * hv; a7 += b1.w * hv;
    }
    if (SLOTS > 1) {
#pragma unroll
        for (int m = F; m < 64; m <<= 1) {
            a0 += __shfl_xor(a0, m, 64); a1 += __shfl_xor(a1, m, 64);
            a2 += __shfl_xor(a2, m, 64); a3 += __shfl_xor(a3, m, 64);
            a4 += __shfl_xor(a4, m, 64); a5 += __shfl_xor(a5, m, 64);
            a6 += __shfl_xor(a6, m, 64); a7 += __shfl_xor(a7, m, 64);
        }
    }
    if (slot == 0) {
        float* Ar = A + (size_t)wid * (8 * F);
        Ar[0 * F + f] = a0; Ar[1 * F + f] = a1; Ar[2 * F + f] = a2; Ar[3 * F + f] = a3;
        Ar[4 * F + f] = a4; Ar[5 * F + f] = a5; Ar[6 * F + f] = a6; Ar[7 * F + f] = a7;
    }
}

// ---------------- dense GEMM: Hout[n, 0..63] = act(A[n, :K] @ W[K, 64]) ----------------
// 256 threads, 64x64 output tile, thread computes 4 rows x 4 cols.

template <int K, bool RELU>
__global__ __launch_bounds__(256) void gemm64_kernel(const float* __restrict__ A,
                                                     const float* __restrict__ W,
                                                     float* __restrict__ Hout, int nN) {
    constexpr int KC = 64;
    __shared__ float Al[64][KC + 4];
    __shared__ float Wl[KC][64];
    int tid = threadIdx.x;
    int n0 = blockIdx.x * 64;
    int o4 = (tid & 15) * 4;
    int r4 = (tid >> 4) * 4;
    float acc[4][4] = {};
    for (int kc = 0; kc < K; kc += KC) {
#pragma unroll
        for (int idx = tid; idx < KC * 64; idx += 256)
            ((float*)Wl)[idx] = W[(size_t)kc * 64 + idx];
#pragma unroll
        for (int p = 0; p < (64 * KC) / 256; p++) {
            int idx = p * 256 + tid;
            int lr = idx >> 6;
            int kk = idx & 63;
            int row = n0 + lr;
            Al[lr][kk] = (row < nN) ? A[(size_t)row * K + kc + kk] : 0.0f;
        }
        __syncthreads();
#pragma unroll 8
        for (int k = 0; k < KC; k++) {
            float4 w = *(const float4*)&Wl[k][o4];
            float b0 = Al[r4 + 0][k], b1 = Al[r4 + 1][k], b2 = Al[r4 + 2][k], b3 = Al[r4 + 3][k];
            acc[0][0] += b0 * w.x; acc[0][1] += b0 * w.y; acc[0][2] += b0 * w.z; acc[0][3] += b0 * w.w;
            acc[1][0] += b1 * w.x; acc[1][1] += b1 * w.y; acc[1][2] += b1 * w.z; acc[1][3] += b1 * w.w;
            acc[2][0] += b2 * w.x; acc[2][1] += b2 * w.y; acc[2][2] += b2 * w.z; acc[2][3] += b2 * w.w;
            acc[3][0] += b3 * w.x; acc[3][1] += b3 * w.y; acc[3][2] += b3 * w.z; acc[3][3] += b3 * w.w;
        }
        __syncthreads();
    }
#pragma unroll
    for (int i = 0; i < 4; i++) {
        int row = n0 + r4 + i;
        if (row < nN) {
            float4 v;
            v.x = acc[i][0]; v.y = acc[i][1]; v.z = acc[i][2]; v.w = acc[i][3];
            if (RELU) {
                v.x = fmaxf(v.x, 0.0f); v.y = fmaxf(v.y, 0.0f);
                v.z = fmaxf(v.z, 0.0f); v.w = fmaxf(v.w, 0.0f);
            }
            *(float4*)&Hout[(size_t)row * 64 + o4] = v;
        }
    }
}

// ---------------- final layer: out[n, 0..1] = (A[n, :512] @ W3[512, 2]) / 128 ----------------
// one wave per node, lanes split K, shfl reduce.

__global__ __launch_bounds__(256) void out_kernel(const float* __restrict__ A,
                                                  const float* __restrict__ W3,
                                                  float* __restrict__ out, int nN) {
    int wid = (blockIdx.x * 256 + threadIdx.x) >> 6;
    int lane = threadIdx.x & 63;
    if (wid >= nN) return;
    const float* Ar = A + (size_t)wid * 512;
    float a0 = 0, a1 = 0;
#pragma unroll
    for (int i = 0; i < 8; i++) {
        int k = lane + i * 64;
        float a = Ar[k];
        float2 w = *(const float2*)&W3[2 * k];
        a0 += a * w.x;
        a1 += a * w.y;
    }
#pragma unroll
    for (int m = 1; m < 64; m <<= 1) {
        a0 += __shfl_xor(a0, m, 64);
        a1 += __shfl_xor(a1, m, 64);
    }
    if (lane == 0) {
        out[(size_t)wid * 2 + 0] = a0 * (1.0f / 128.0f);
        out[(size_t)wid * 2 + 1] = a1 * (1.0f / 128.0f);
    }
}

// ---------------- launch ----------------

extern "C" void kernel_launch(void* const* d_in, const int* in_sizes, int n_in,
                              void* d_out, int out_size, void* d_ws, size_t ws_size,
                              hipStream_t stream) {
    const float* x  = (const float*)d_in[0];
    const int*   ei = (const int*)d_in[1];
    const float* el = (const float*)d_in[2];
    const float* W0 = (const float*)d_in[3];
    const float* W1 = (const float*)d_in[4];
    const float* W2 = (const float*)d_in[5];
    const float* W3 = (const float*)d_in[6];
    int nN = in_sizes[0] / 16;
    int E  = in_sizes[1] / 2;
    const int* src = ei;
    const int* dst = ei + E;

    char* ws = (char*)d_ws;
    size_t off = 0;
    auto alloc = [&](size_t bytes) -> void* {
        void* p = ws + off;
        off = (off + bytes + 255) & ~(size_t)255;
        return p;
    };
    int*   cntcur = (int*)alloc((size_t)(nN + 1) * 4);
    int*   offs   = (int*)alloc((size_t)(nN + 1) * 4);
    int*   srcS   = (int*)alloc((size_t)E * 4);
    float* basisS = (float*)alloc((size_t)E * 8 * 4);
    float* A      = (float*)alloc((size_t)nN * 512 * 4);
    float* hA     = (float*)alloc((size_t)nN * 64 * 4);
    float* hB     = (float*)alloc((size_t)nN * 64 * 4);
    (void)ws_size;

    hipMemsetAsync(cntcur, 0, (size_t)nN * 4, stream);
    int eb = (E + 255) / 256;
    count_kernel<<<eb, 256, 0, stream>>>(dst, cntcur, E);
    scan_kernel<<<1, 1024, 0, stream>>>(cntcur, offs, nN, E);
    fill_kernel<<<eb, 256, 0, stream>>>(src, dst, el, cntcur, srcS, basisS, E);

    int nb = (nN + 3) / 4;    // wave-per-node kernels
    int gb = (nN + 63) / 64;  // gemm tiles

    // layer 0: in=16 -> 64
    agg_kernel<16><<<nb, 256, 0, stream>>>(x, srcS, basisS, offs, A, nN);
    gemm64_kernel<128, true><<<gb, 256, 0, stream>>>(A, W0, hA, nN);
    // layer 1: 64 -> 64
    agg_kernel<64><<<nb, 256, 0, stream>>>(hA, srcS, basisS, offs, A, nN);
    gemm64_kernel<512, true><<<gb, 256, 0, stream>>>(A, W1, hB, nN);
    // layer 2: 64 -> 64
    agg_kernel<64><<<nb, 256, 0, stream>>>(hB, srcS, basisS, offs, A, nN);
    gemm64_kernel<512, true><<<gb, 256, 0, stream>>>(A, W2, hA, nN);
    // layer 3: 64 -> 2 (+ output scaling)
    agg_kernel<64><<<nb, 256, 0, stream>>>(hA, srcS, basisS, offs, A, nN);
    out_kernel<<<nb, 256, 0, stream>>>(A, W3, (float*)d_out, nN);
}

// Round 2
// 707.257 us; speedup vs baseline: 1.1729x; 1.1729x over previous
//
#include <hip/hip_runtime.h>
#include <math.h>

#define PI_F 3.14159265358979323846f

// ---------------- binning (counting sort by dst) ----------------

__global__ void count_kernel(const int* __restrict__ dst, int* __restrict__ cnt, int E) {
    int e = blockIdx.x * 256 + threadIdx.x;
    if (e < E) atomicAdd(&cnt[dst[e]], 1);
}

// hierarchical scan, stage 1: per-block (256 elems) reduce -> bsum[block]
__global__ __launch_bounds__(256) void scan_reduce_kernel(const int* __restrict__ cnt,
                                                          int* __restrict__ bsum, int n) {
    __shared__ int sd[4];
    int idx = blockIdx.x * 256 + threadIdx.x;
    int v = (idx < n) ? cnt[idx] : 0;
    int s = v;
#pragma unroll
    for (int m = 1; m < 64; m <<= 1) s += __shfl_xor(s, m, 64);
    int wave = threadIdx.x >> 6;
    if ((threadIdx.x & 63) == 0) sd[wave] = s;
    __syncthreads();
    if (threadIdx.x == 0) bsum[blockIdx.x] = sd[0] + sd[1] + sd[2] + sd[3];
}

// stage 2: one block, exclusive scan of nb (<=256) block sums -> boffs
__global__ __launch_bounds__(256) void scan_top_kernel(const int* __restrict__ bsum,
                                                       int* __restrict__ boffs, int nb) {
    __shared__ int sd[256];
    int tid = threadIdx.x;
    int v = (tid < nb) ? bsum[tid] : 0;
    sd[tid] = v;
    __syncthreads();
#pragma unroll
    for (int off = 1; off < 256; off <<= 1) {
        int t = (tid >= off) ? sd[tid - off] : 0;
        __syncthreads();
        sd[tid] += t;
        __syncthreads();
    }
    if (tid < nb) boffs[tid] = sd[tid] - v;  // exclusive
}

// stage 3: per-block exclusive scan of its 256 elems + block offset; writes
// offs[] and initializes cursor[] (same array as cnt, overwritten in place).
__global__ __launch_bounds__(256) void scan_apply_kernel(int* __restrict__ cntcur,
                                                         int* __restrict__ offs,
                                                         const int* __restrict__ boffs,
                                                         int n, int total) {
    __shared__ int sd[256];
    int tid = threadIdx.x;
    int idx = blockIdx.x * 256 + tid;
    int v = (idx < n) ? cntcur[idx] : 0;
    sd[tid] = v;
    __syncthreads();
#pragma unroll
    for (int off = 1; off < 256; off <<= 1) {
        int t = (tid >= off) ? sd[tid - off] : 0;
        __syncthreads();
        sd[tid] += t;
        __syncthreads();
    }
    if (idx < n) {
        int ex = boffs[blockIdx.x] + sd[tid] - v;
        offs[idx] = ex;
        cntcur[idx] = ex;  // cursor for fill pass
    }
    if (idx == 0) offs[n] = total;
}

// scatter edges into dst-bins; compute fourier basis once, into bin order.
// basis per dim: [1, sin(pi x), cos(pi x), sin(2 pi x)]
__global__ void fill_kernel(const int* __restrict__ src, const int* __restrict__ dst,
                            const float* __restrict__ el, int* __restrict__ cursor,
                            int* __restrict__ srcS, float* __restrict__ basisS, int E) {
    int e = blockIdx.x * 256 + threadIdx.x;
    if (e >= E) return;
    int d = dst[e];
    int pos = atomicAdd(&cursor[d], 1);
    srcS[pos] = src[e];
    float2 xy = *(const float2*)(el + 2 * (size_t)e);
    float4 b0, b1;
    b0.x = 1.0f; b0.y = __sinf(PI_F * xy.x); b0.z = __cosf(PI_F * xy.x); b0.w = __sinf(2.0f * PI_F * xy.x);
    b1.x = 1.0f; b1.y = __sinf(PI_F * xy.y); b1.z = __cosf(PI_F * xy.y); b1.w = __sinf(2.0f * PI_F * xy.y);
    float4* bp = (float4*)(basisS + (size_t)pos * 8);
    bp[0] = b0;
    bp[1] = b1;
}

// ---------------- per-layer: edge aggregation into A[n, 8*F] ----------------
// one wave per dst node; lane -> feature f (F=64) or (f, edge-slot) (F=16).
// A[n][b*F + f] = sum over incoming edges of basis[e][b] * h[src][f]

template <int F>
__global__ __launch_bounds__(256) void agg_kernel(const float* __restrict__ h,
                                                  const int* __restrict__ srcS,
                                                  const float* __restrict__ basisS,
                                                  const int* __restrict__ offs,
                                                  float* __restrict__ A, int nN) {
    constexpr int SLOTS = 64 / F;
    int wid = (blockIdx.x * 256 + threadIdx.x) >> 6;
    int lane = threadIdx.x & 63;
    if (wid >= nN) return;
    int f = lane & (F - 1);
    int slot = lane / F;
    int start = offs[wid], end = offs[wid + 1];
    float a0 = 0, a1 = 0, a2 = 0, a3 = 0, a4 = 0, a5 = 0, a6 = 0, a7 = 0;
    for (int j = start + slot; j < end; j += SLOTS) {
        int s = srcS[j];
        float hv = h[(size_t)s * F + f];
        const float4* bp = (const float4*)(basisS + (size_t)j * 8);
        float4 b0 = bp[0];
        float4 b1 = bp[1];
        a0 += b0.x * hv; a1 += b0.y * hv; a2 += b0.z * hv; a3 += b0.w * hv;
        a4 += b1.x * hv; a5 += b1.y * hv; a6 += b1.z * hv; a7 += b1.w * hv;
    }
    if (SLOTS > 1) {
#pragma unroll
        for (int m = F; m < 64; m <<= 1) {
            a0 += __shfl_xor(a0, m, 64); a1 += __shfl_xor(a1, m, 64);
            a2 += __shfl_xor(a2, m, 64); a3 += __shfl_xor(a3, m, 64);
            a4 += __shfl_xor(a4, m, 64); a5 += __shfl_xor(a5, m, 64);
            a6 += __shfl_xor(a6, m, 64); a7 += __shfl_xor(a7, m, 64);
        }
    }
    if (slot == 0) {
        float* Ar = A + (size_t)wid * (8 * F);
        Ar[0 * F + f] = a0; Ar[1 * F + f] = a1; Ar[2 * F + f] = a2; Ar[3 * F + f] = a3;
        Ar[4 * F + f] = a4; Ar[5 * F + f] = a5; Ar[6 * F + f] = a6; Ar[7 * F + f] = a7;
    }
}

// ---------------- fused final layer: agg (F=64) + [512x2] contraction + scale ----------------
// one wave per node; lane = feature f; a[b] = A[n][b*64+f] in registers.
// out[n,o] = (1/128) * sum_{b,f} a[b,f] * W3[(b*64+f)*2 + o]

__global__ __launch_bounds__(256) void agg_out_kernel(const float* __restrict__ h,
                                                      const int* __restrict__ srcS,
                                                      const float* __restrict__ basisS,
                                                      const int* __restrict__ offs,
                                                      const float* __restrict__ W3,
                                                      float* __restrict__ out, int nN) {
    int wid = (blockIdx.x * 256 + threadIdx.x) >> 6;
    int lane = threadIdx.x & 63;
    if (wid >= nN) return;
    int start = offs[wid], end = offs[wid + 1];
    float a0 = 0, a1 = 0, a2 = 0, a3 = 0, a4 = 0, a5 = 0, a6 = 0, a7 = 0;
    for (int j = start; j < end; j++) {
        int s = srcS[j];
        float hv = h[(size_t)s * 64 + lane];
        const float4* bp = (const float4*)(basisS + (size_t)j * 8);
        float4 b0 = bp[0];
        float4 b1 = bp[1];
        a0 += b0.x * hv; a1 += b0.y * hv; a2 += b0.z * hv; a3 += b0.w * hv;
        a4 += b1.x * hv; a5 += b1.y * hv; a6 += b1.z * hv; a7 += b1.w * hv;
    }
    float o0 = 0, o1 = 0;
    float aa[8] = {a0, a1, a2, a3, a4, a5, a6, a7};
#pragma unroll
    for (int b = 0; b < 8; b++) {
        float2 w = *(const float2*)&W3[(size_t)(b * 64 + lane) * 2];
        o0 += aa[b] * w.x;
        o1 += aa[b] * w.y;
    }
#pragma unroll
    for (int m = 1; m < 64; m <<= 1) {
        o0 += __shfl_xor(o0, m, 64);
        o1 += __shfl_xor(o1, m, 64);
    }
    if (lane == 0) {
        out[(size_t)wid * 2 + 0] = o0 * (1.0f / 128.0f);
        out[(size_t)wid * 2 + 1] = o1 * (1.0f / 128.0f);
    }
}

// ---------------- dense GEMM: Hout[n, 0..63] = act(A[n, :K] @ W[K, 64]) ----------------
// 256 threads, 64x64 output tile, thread computes 4 rows x 4 cols.

template <int K, bool RELU>
__global__ __launch_bounds__(256) void gemm64_kernel(const float* __restrict__ A,
                                                     const float* __restrict__ W,
                                                     float* __restrict__ Hout, int nN) {
    constexpr int KC = 64;
    __shared__ float Al[64][KC + 4];
    __shared__ float Wl[KC][64];
    int tid = threadIdx.x;
    int n0 = blockIdx.x * 64;
    int o4 = (tid & 15) * 4;
    int r4 = (tid >> 4) * 4;
    float acc[4][4] = {};
    for (int kc = 0; kc < K; kc += KC) {
#pragma unroll
        for (int idx = tid; idx < KC * 64; idx += 256)
            ((float*)Wl)[idx] = W[(size_t)kc * 64 + idx];
#pragma unroll
        for (int p = 0; p < (64 * KC) / 256; p++) {
            int idx = p * 256 + tid;
            int lr = idx >> 6;
            int kk = idx & 63;
            int row = n0 + lr;
            Al[lr][kk] = (row < nN) ? A[(size_t)row * K + kc + kk] : 0.0f;
        }
        __syncthreads();
#pragma unroll 8
        for (int k = 0; k < KC; k++) {
            float4 w = *(const float4*)&Wl[k][o4];
            float b0 = Al[r4 + 0][k], b1 = Al[r4 + 1][k], b2 = Al[r4 + 2][k], b3 = Al[r4 + 3][k];
            acc[0][0] += b0 * w.x; acc[0][1] += b0 * w.y; acc[0][2] += b0 * w.z; acc[0][3] += b0 * w.w;
            acc[1][0] += b1 * w.x; acc[1][1] += b1 * w.y; acc[1][2] += b1 * w.z; acc[1][3] += b1 * w.w;
            acc[2][0] += b2 * w.x; acc[2][1] += b2 * w.y; acc[2][2] += b2 * w.z; acc[2][3] += b2 * w.w;
            acc[3][0] += b3 * w.x; acc[3][1] += b3 * w.y; acc[3][2] += b3 * w.z; acc[3][3] += b3 * w.w;
        }
        __syncthreads();
    }
#pragma unroll
    for (int i = 0; i < 4; i++) {
        int row = n0 + r4 + i;
        if (row < nN) {
            float4 v;
            v.x = acc[i][0]; v.y = acc[i][1]; v.z = acc[i][2]; v.w = acc[i][3];
            if (RELU) {
                v.x = fmaxf(v.x, 0.0f); v.y = fmaxf(v.y, 0.0f);
                v.z = fmaxf(v.z, 0.0f); v.w = fmaxf(v.w, 0.0f);
            }
            *(float4*)&Hout[(size_t)row * 64 + o4] = v;
        }
    }
}

// ---------------- launch ----------------

extern "C" void kernel_launch(void* const* d_in, const int* in_sizes, int n_in,
                              void* d_out, int out_size, void* d_ws, size_t ws_size,
                              hipStream_t stream) {
    const float* x  = (const float*)d_in[0];
    const int*   ei = (const int*)d_in[1];
    const float* el = (const float*)d_in[2];
    const float* W0 = (const float*)d_in[3];
    const float* W1 = (const float*)d_in[4];
    const float* W2 = (const float*)d_in[5];
    const float* W3 = (const float*)d_in[6];
    int nN = in_sizes[0] / 16;
    int E  = in_sizes[1] / 2;
    const int* src = ei;
    const int* dst = ei + E;

    char* ws = (char*)d_ws;
    size_t off = 0;
    auto alloc = [&](size_t bytes) -> void* {
        void* p = ws + off;
        off = (off + bytes + 255) & ~(size_t)255;
        return p;
    };
    int nsb = (nN + 255) / 256;  // scan blocks (must be <= 256)
    int*   cntcur = (int*)alloc((size_t)(nN + 1) * 4);
    int*   offs   = (int*)alloc((size_t)(nN + 1) * 4);
    int*   bsum   = (int*)alloc((size_t)nsb * 4);
    int*   boffs  = (int*)alloc((size_t)nsb * 4);
    int*   srcS   = (int*)alloc((size_t)E * 4);
    float* basisS = (float*)alloc((size_t)E * 8 * 4);
    float* A      = (float*)alloc((size_t)nN * 512 * 4);
    float* hA     = (float*)alloc((size_t)nN * 64 * 4);
    float* hB     = (float*)alloc((size_t)nN * 64 * 4);
    (void)ws_size;

    hipMemsetAsync(cntcur, 0, (size_t)nN * 4, stream);
    int eb = (E + 255) / 256;
    count_kernel<<<eb, 256, 0, stream>>>(dst, cntcur, E);
    scan_reduce_kernel<<<nsb, 256, 0, stream>>>(cntcur, bsum, nN);
    scan_top_kernel<<<1, 256, 0, stream>>>(bsum, boffs, nsb);
    scan_apply_kernel<<<nsb, 256, 0, stream>>>(cntcur, offs, boffs, nN, E);
    fill_kernel<<<eb, 256, 0, stream>>>(src, dst, el, cntcur, srcS, basisS, E);

    int nb = (nN + 3) / 4;    // wave-per-node kernels
    int gb = (nN + 63) / 64;  // gemm tiles

    // layer 0: in=16 -> 64
    agg_kernel<16><<<nb, 256, 0, stream>>>(x, srcS, basisS, offs, A, nN);
    gemm64_kernel<128, true><<<gb, 256, 0, stream>>>(A, W0, hA, nN);
    // layer 1: 64 -> 64
    agg_kernel<64><<<nb, 256, 0, stream>>>(hA, srcS, basisS, offs, A, nN);
    gemm64_kernel<512, true><<<gb, 256, 0, stream>>>(A, W1, hB, nN);
    // layer 2: 64 -> 64
    agg_kernel<64><<<nb, 256, 0, stream>>>(hB, srcS, basisS, offs, A, nN);
    gemm64_kernel<512, true><<<gb, 256, 0, stream>>>(A, W2, hA, nN);
    // layer 3 fused: agg + [512x2] + scale
    agg_out_kernel<<<nb, 256, 0, stream>>>(hA, srcS, basisS, offs, W3, (float*)d_out, nN);
}

// Round 3
// 613.529 us; speedup vs baseline: 1.3521x; 1.1528x over previous
//
#include <hip/hip_runtime.h>
#include <math.h>

#define PI_F 3.14159265358979323846f

// ---------------- binning (counting sort by dst) ----------------

__global__ void count_kernel(const int* __restrict__ dst, int* __restrict__ cnt, int E) {
    int e = blockIdx.x * 256 + threadIdx.x;
    if (e < E) atomicAdd(&cnt[dst[e]], 1);
}

// hierarchical scan, stage 1: per-block (256 elems) reduce -> bsum[block]
__global__ __launch_bounds__(256) void scan_reduce_kernel(const int* __restrict__ cnt,
                                                          int* __restrict__ bsum, int n) {
    __shared__ int sd[4];
    int idx = blockIdx.x * 256 + threadIdx.x;
    int v = (idx < n) ? cnt[idx] : 0;
    int s = v;
#pragma unroll
    for (int m = 1; m < 64; m <<= 1) s += __shfl_xor(s, m, 64);
    int wave = threadIdx.x >> 6;
    if ((threadIdx.x & 63) == 0) sd[wave] = s;
    __syncthreads();
    if (threadIdx.x == 0) bsum[blockIdx.x] = sd[0] + sd[1] + sd[2] + sd[3];
}

// stage 2: one block, exclusive scan of nb (<=256) block sums -> boffs
__global__ __launch_bounds__(256) void scan_top_kernel(const int* __restrict__ bsum,
                                                       int* __restrict__ boffs, int nb) {
    __shared__ int sd[256];
    int tid = threadIdx.x;
    int v = (tid < nb) ? bsum[tid] : 0;
    sd[tid] = v;
    __syncthreads();
#pragma unroll
    for (int off = 1; off < 256; off <<= 1) {
        int t = (tid >= off) ? sd[tid - off] : 0;
        __syncthreads();
        sd[tid] += t;
        __syncthreads();
    }
    if (tid < nb) boffs[tid] = sd[tid] - v;  // exclusive
}

// stage 3: per-block exclusive scan of its 256 elems + block offset; writes
// offs[] and initializes cursor[] (same array as cnt, overwritten in place).
__global__ __launch_bounds__(256) void scan_apply_kernel(int* __restrict__ cntcur,
                                                         int* __restrict__ offs,
                                                         const int* __restrict__ boffs,
                                                         int n, int total) {
    __shared__ int sd[256];
    int tid = threadIdx.x;
    int idx = blockIdx.x * 256 + tid;
    int v = (idx < n) ? cntcur[idx] : 0;
    sd[tid] = v;
    __syncthreads();
#pragma unroll
    for (int off = 1; off < 256; off <<= 1) {
        int t = (tid >= off) ? sd[tid - off] : 0;
        __syncthreads();
        sd[tid] += t;
        __syncthreads();
    }
    if (idx < n) {
        int ex = boffs[blockIdx.x] + sd[tid] - v;
        offs[idx] = ex;
        cntcur[idx] = ex;  // cursor for fill pass
    }
    if (idx == 0) offs[n] = total;
}

// scatter edges into dst-bins; compute fourier basis once, into bin order.
// basis per dim: [1, sin(pi x), cos(pi x), sin(2 pi x)]
__global__ void fill_kernel(const int* __restrict__ src, const int* __restrict__ dst,
                            const float* __restrict__ el, int* __restrict__ cursor,
                            int* __restrict__ srcS, float* __restrict__ basisS, int E) {
    int e = blockIdx.x * 256 + threadIdx.x;
    if (e >= E) return;
    int d = dst[e];
    int pos = atomicAdd(&cursor[d], 1);
    srcS[pos] = src[e];
    float2 xy = *(const float2*)(el + 2 * (size_t)e);
    float4 b0, b1;
    b0.x = 1.0f; b0.y = __sinf(PI_F * xy.x); b0.z = __cosf(PI_F * xy.x); b0.w = __sinf(2.0f * PI_F * xy.x);
    b1.x = 1.0f; b1.y = __sinf(PI_F * xy.y); b1.z = __cosf(PI_F * xy.y); b1.w = __sinf(2.0f * PI_F * xy.y);
    float4* bp = (float4*)(basisS + (size_t)pos * 8);
    bp[0] = b0;
    bp[1] = b1;
}

// ---------------- per-layer: edge aggregation into A[n, 8*F] ----------------
// one wave per dst node; lane -> feature f (F=64) or (f, edge-slot) (F=16).
// A[n][b*F + f] = sum over incoming edges of basis[e][b] * h[src][f]
// 4-deep software pipeline: batch 4 edges' loads (independent) before FMAs.

template <int F>
__global__ __launch_bounds__(256) void agg_kernel(const float* __restrict__ h,
                                                  const int* __restrict__ srcS,
                                                  const float* __restrict__ basisS,
                                                  const int* __restrict__ offs,
                                                  float* __restrict__ A, int nN) {
    constexpr int SLOTS = 64 / F;
    int wid = (blockIdx.x * 256 + threadIdx.x) >> 6;
    int lane = threadIdx.x & 63;
    if (wid >= nN) return;
    int f = lane & (F - 1);
    int slot = lane / F;
    int start = offs[wid], end = offs[wid + 1];
    float a0 = 0, a1 = 0, a2 = 0, a3 = 0, a4 = 0, a5 = 0, a6 = 0, a7 = 0;
    const float4* bp = (const float4*)basisS;
    int j = start + slot;
    for (; j + 3 * SLOTS < end; j += 4 * SLOTS) {
        int j0 = j, j1 = j + SLOTS, j2 = j + 2 * SLOTS, j3 = j + 3 * SLOTS;
        int s0 = srcS[j0], s1 = srcS[j1], s2 = srcS[j2], s3 = srcS[j3];
        float h0 = h[(size_t)s0 * F + f];
        float h1 = h[(size_t)s1 * F + f];
        float h2 = h[(size_t)s2 * F + f];
        float h3 = h[(size_t)s3 * F + f];
        float4 c00 = bp[2 * j0], c01 = bp[2 * j0 + 1];
        float4 c10 = bp[2 * j1], c11 = bp[2 * j1 + 1];
        float4 c20 = bp[2 * j2], c21 = bp[2 * j2 + 1];
        float4 c30 = bp[2 * j3], c31 = bp[2 * j3 + 1];
        a0 += c00.x * h0; a1 += c00.y * h0; a2 += c00.z * h0; a3 += c00.w * h0;
        a4 += c01.x * h0; a5 += c01.y * h0; a6 += c01.z * h0; a7 += c01.w * h0;
        a0 += c10.x * h1; a1 += c10.y * h1; a2 += c10.z * h1; a3 += c10.w * h1;
        a4 += c11.x * h1; a5 += c11.y * h1; a6 += c11.z * h1; a7 += c11.w * h1;
        a0 += c20.x * h2; a1 += c20.y * h2; a2 += c20.z * h2; a3 += c20.w * h2;
        a4 += c21.x * h2; a5 += c21.y * h2; a6 += c21.z * h2; a7 += c21.w * h2;
        a0 += c30.x * h3; a1 += c30.y * h3; a2 += c30.z * h3; a3 += c30.w * h3;
        a4 += c31.x * h3; a5 += c31.y * h3; a6 += c31.z * h3; a7 += c31.w * h3;
    }
    for (; j < end; j += SLOTS) {
        int s = srcS[j];
        float hv = h[(size_t)s * F + f];
        float4 b0 = bp[2 * j], b1 = bp[2 * j + 1];
        a0 += b0.x * hv; a1 += b0.y * hv; a2 += b0.z * hv; a3 += b0.w * hv;
        a4 += b1.x * hv; a5 += b1.y * hv; a6 += b1.z * hv; a7 += b1.w * hv;
    }
    if (SLOTS > 1) {
#pragma unroll
        for (int m = F; m < 64; m <<= 1) {
            a0 += __shfl_xor(a0, m, 64); a1 += __shfl_xor(a1, m, 64);
            a2 += __shfl_xor(a2, m, 64); a3 += __shfl_xor(a3, m, 64);
            a4 += __shfl_xor(a4, m, 64); a5 += __shfl_xor(a5, m, 64);
            a6 += __shfl_xor(a6, m, 64); a7 += __shfl_xor(a7, m, 64);
        }
    }
    if (slot == 0) {
        float* Ar = A + (size_t)wid * (8 * F);
        Ar[0 * F + f] = a0; Ar[1 * F + f] = a1; Ar[2 * F + f] = a2; Ar[3 * F + f] = a3;
        Ar[4 * F + f] = a4; Ar[5 * F + f] = a5; Ar[6 * F + f] = a6; Ar[7 * F + f] = a7;
    }
}

// ---------------- fused final layer: agg (F=64) + [512x2] contraction + scale ----------------

__global__ __launch_bounds__(256) void agg_out_kernel(const float* __restrict__ h,
                                                      const int* __restrict__ srcS,
                                                      const float* __restrict__ basisS,
                                                      const int* __restrict__ offs,
                                                      const float* __restrict__ W3,
                                                      float* __restrict__ out, int nN) {
    int wid = (blockIdx.x * 256 + threadIdx.x) >> 6;
    int lane = threadIdx.x & 63;
    if (wid >= nN) return;
    int start = offs[wid], end = offs[wid + 1];
    float a0 = 0, a1 = 0, a2 = 0, a3 = 0, a4 = 0, a5 = 0, a6 = 0, a7 = 0;
    const float4* bp = (const float4*)basisS;
    int j = start;
    for (; j + 3 < end; j += 4) {
        int s0 = srcS[j], s1 = srcS[j + 1], s2 = srcS[j + 2], s3 = srcS[j + 3];
        float h0 = h[(size_t)s0 * 64 + lane];
        float h1 = h[(size_t)s1 * 64 + lane];
        float h2 = h[(size_t)s2 * 64 + lane];
        float h3 = h[(size_t)s3 * 64 + lane];
        float4 c00 = bp[2 * j], c01 = bp[2 * j + 1];
        float4 c10 = bp[2 * j + 2], c11 = bp[2 * j + 3];
        float4 c20 = bp[2 * j + 4], c21 = bp[2 * j + 5];
        float4 c30 = bp[2 * j + 6], c31 = bp[2 * j + 7];
        a0 += c00.x * h0; a1 += c00.y * h0; a2 += c00.z * h0; a3 += c00.w * h0;
        a4 += c01.x * h0; a5 += c01.y * h0; a6 += c01.z * h0; a7 += c01.w * h0;
        a0 += c10.x * h1; a1 += c10.y * h1; a2 += c10.z * h1; a3 += c10.w * h1;
        a4 += c11.x * h1; a5 += c11.y * h1; a6 += c11.z * h1; a7 += c11.w * h1;
        a0 += c20.x * h2; a1 += c20.y * h2; a2 += c20.z * h2; a3 += c20.w * h2;
        a4 += c21.x * h2; a5 += c21.y * h2; a6 += c21.z * h2; a7 += c21.w * h2;
        a0 += c30.x * h3; a1 += c30.y * h3; a2 += c30.z * h3; a3 += c30.w * h3;
        a4 += c31.x * h3; a5 += c31.y * h3; a6 += c31.z * h3; a7 += c31.w * h3;
    }
    for (; j < end; j++) {
        int s = srcS[j];
        float hv = h[(size_t)s * 64 + lane];
        float4 b0 = bp[2 * j], b1 = bp[2 * j + 1];
        a0 += b0.x * hv; a1 += b0.y * hv; a2 += b0.z * hv; a3 += b0.w * hv;
        a4 += b1.x * hv; a5 += b1.y * hv; a6 += b1.z * hv; a7 += b1.w * hv;
    }
    float o0 = 0, o1 = 0;
    float aa[8] = {a0, a1, a2, a3, a4, a5, a6, a7};
#pragma unroll
    for (int b = 0; b < 8; b++) {
        float2 w = *(const float2*)&W3[(size_t)(b * 64 + lane) * 2];
        o0 += aa[b] * w.x;
        o1 += aa[b] * w.y;
    }
#pragma unroll
    for (int m = 1; m < 64; m <<= 1) {
        o0 += __shfl_xor(o0, m, 64);
        o1 += __shfl_xor(o1, m, 64);
    }
    if (lane == 0) {
        out[(size_t)wid * 2 + 0] = o0 * (1.0f / 128.0f);
        out[(size_t)wid * 2 + 1] = o1 * (1.0f / 128.0f);
    }
}

// ---------------- dense GEMM: Hout[n, 0..63] = act(A[n, :K] @ W[K, 64]) ----------------

template <int K, bool RELU>
__global__ __launch_bounds__(256) void gemm64_kernel(const float* __restrict__ A,
                                                     const float* __restrict__ W,
                                                     float* __restrict__ Hout, int nN) {
    constexpr int KC = 64;
    __shared__ float Al[64][KC + 4];
    __shared__ float Wl[KC][64];
    int tid = threadIdx.x;
    int n0 = blockIdx.x * 64;
    int o4 = (tid & 15) * 4;
    int r4 = (tid >> 4) * 4;
    float acc[4][4] = {};
    for (int kc = 0; kc < K; kc += KC) {
#pragma unroll
        for (int idx = tid; idx < KC * 64; idx += 256)
            ((float*)Wl)[idx] = W[(size_t)kc * 64 + idx];
#pragma unroll
        for (int p = 0; p < (64 * KC) / 256; p++) {
            int idx = p * 256 + tid;
            int lr = idx >> 6;
            int kk = idx & 63;
            int row = n0 + lr;
            Al[lr][kk] = (row < nN) ? A[(size_t)row * K + kc + kk] : 0.0f;
        }
        __syncthreads();
#pragma unroll 8
        for (int k = 0; k < KC; k++) {
            float4 w = *(const float4*)&Wl[k][o4];
            float b0 = Al[r4 + 0][k], b1 = Al[r4 + 1][k], b2 = Al[r4 + 2][k], b3 = Al[r4 + 3][k];
            acc[0][0] += b0 * w.x; acc[0][1] += b0 * w.y; acc[0][2] += b0 * w.z; acc[0][3] += b0 * w.w;
            acc[1][0] += b1 * w.x; acc[1][1] += b1 * w.y; acc[1][2] += b1 * w.z; acc[1][3] += b1 * w.w;
            acc[2][0] += b2 * w.x; acc[2][1] += b2 * w.y; acc[2][2] += b2 * w.z; acc[2][3] += b2 * w.w;
            acc[3][0] += b3 * w.x; acc[3][1] += b3 * w.y; acc[3][2] += b3 * w.z; acc[3][3] += b3 * w.w;
        }
        __syncthreads();
    }
#pragma unroll
    for (int i = 0; i < 4; i++) {
        int row = n0 + r4 + i;
        if (row < nN) {
            float4 v;
            v.x = acc[i][0]; v.y = acc[i][1]; v.z = acc[i][2]; v.w = acc[i][3];
            if (RELU) {
                v.x = fmaxf(v.x, 0.0f); v.y = fmaxf(v.y, 0.0f);
                v.z = fmaxf(v.z, 0.0f); v.w = fmaxf(v.w, 0.0f);
            }
            *(float4*)&Hout[(size_t)row * 64 + o4] = v;
        }
    }
}

// ---------------- launch ----------------

extern "C" void kernel_launch(void* const* d_in, const int* in_sizes, int n_in,
                              void* d_out, int out_size, void* d_ws, size_t ws_size,
                              hipStream_t stream) {
    const float* x  = (const float*)d_in[0];
    const int*   ei = (const int*)d_in[1];
    const float* el = (const float*)d_in[2];
    const float* W0 = (const float*)d_in[3];
    const float* W1 = (const float*)d_in[4];
    const float* W2 = (const float*)d_in[5];
    const float* W3 = (const float*)d_in[6];
    int nN = in_sizes[0] / 16;
    int E  = in_sizes[1] / 2;
    const int* src = ei;
    const int* dst = ei + E;

    char* ws = (char*)d_ws;
    size_t off = 0;
    auto alloc = [&](size_t bytes) -> void* {
        void* p = ws + off;
        off = (off + bytes + 255) & ~(size_t)255;
        return p;
    };
    int nsb = (nN + 255) / 256;  // scan blocks (must be <= 256)
    int*   cntcur = (int*)alloc((size_t)(nN + 1) * 4);
    int*   offs   = (int*)alloc((size_t)(nN + 1) * 4);
    int*   bsum   = (int*)alloc((size_t)nsb * 4);
    int*   boffs  = (int*)alloc((size_t)nsb * 4);
    int*   srcS   = (int*)alloc((size_t)E * 4);
    float* basisS = (float*)alloc((size_t)E * 8 * 4);
    float* A      = (float*)alloc((size_t)nN * 512 * 4);
    float* hA     = (float*)alloc((size_t)nN * 64 * 4);
    float* hB     = (float*)alloc((size_t)nN * 64 * 4);
    (void)ws_size;

    hipMemsetAsync(cntcur, 0, (size_t)nN * 4, stream);
    int eb = (E + 255) / 256;
    count_kernel<<<eb, 256, 0, stream>>>(dst, cntcur, E);
    scan_reduce_kernel<<<nsb, 256, 0, stream>>>(cntcur, bsum, nN);
    scan_top_kernel<<<1, 256, 0, stream>>>(bsum, boffs, nsb);
    scan_apply_kernel<<<nsb, 256, 0, stream>>>(cntcur, offs, boffs, nN, E);
    fill_kernel<<<eb, 256, 0, stream>>>(src, dst, el, cntcur, srcS, basisS, E);

    int nb = (nN + 3) / 4;    // wave-per-node kernels
    int gb = (nN + 63) / 64;  // gemm tiles

    // layer 0: in=16 -> 64
    agg_kernel<16><<<nb, 256, 0, stream>>>(x, srcS, basisS, offs, A, nN);
    gemm64_kernel<128, true><<<gb, 256, 0, stream>>>(A, W0, hA, nN);
    // layer 1: 64 -> 64
    agg_kernel<64><<<nb, 256, 0, stream>>>(hA, srcS, basisS, offs, A, nN);
    gemm64_kernel<512, true><<<gb, 256, 0, stream>>>(A, W1, hB, nN);
    // layer 2: 64 -> 64
    agg_kernel<64><<<nb, 256, 0, stream>>>(hB, srcS, basisS, offs, A, nN);
    gemm64_kernel<512, true><<<gb, 256, 0, stream>>>(A, W2, hA, nN);
    // layer 3 fused: agg + [512x2] + scale
    agg_out_kernel<<<nb, 256, 0, stream>>>(hA, srcS, basisS, offs, W3, (float*)d_out, nN);
}

// Round 4
// 510.056 us; speedup vs baseline: 1.6264x; 1.2029x over previous
//
#include <hip/hip_runtime.h>
#include <hip/hip_bf16.h>
#include <math.h>

#define PI_F 3.14159265358979323846f

typedef __attribute__((ext_vector_type(8))) short bf16x8;
typedef __attribute__((ext_vector_type(4))) float f32x4;

// ---------------- binning (counting sort by dst) ----------------

__global__ void count_kernel(const int* __restrict__ dst, int* __restrict__ cnt, int E) {
    int e = blockIdx.x * 256 + threadIdx.x;
    if (e < E) atomicAdd(&cnt[dst[e]], 1);
}

__global__ __launch_bounds__(256) void scan_reduce_kernel(const int* __restrict__ cnt,
                                                          int* __restrict__ bsum, int n) {
    __shared__ int sd[4];
    int idx = blockIdx.x * 256 + threadIdx.x;
    int v = (idx < n) ? cnt[idx] : 0;
    int s = v;
#pragma unroll
    for (int m = 1; m < 64; m <<= 1) s += __shfl_xor(s, m, 64);
    int wave = threadIdx.x >> 6;
    if ((threadIdx.x & 63) == 0) sd[wave] = s;
    __syncthreads();
    if (threadIdx.x == 0) bsum[blockIdx.x] = sd[0] + sd[1] + sd[2] + sd[3];
}

__global__ __launch_bounds__(256) void scan_top_kernel(const int* __restrict__ bsum,
                                                       int* __restrict__ boffs, int nb) {
    __shared__ int sd[256];
    int tid = threadIdx.x;
    int v = (tid < nb) ? bsum[tid] : 0;
    sd[tid] = v;
    __syncthreads();
#pragma unroll
    for (int off = 1; off < 256; off <<= 1) {
        int t = (tid >= off) ? sd[tid - off] : 0;
        __syncthreads();
        sd[tid] += t;
        __syncthreads();
    }
    if (tid < nb) boffs[tid] = sd[tid] - v;  // exclusive
}

__global__ __launch_bounds__(256) void scan_apply_kernel(int* __restrict__ cntcur,
                                                         int* __restrict__ offs,
                                                         const int* __restrict__ boffs,
                                                         int n, int total) {
    __shared__ int sd[256];
    int tid = threadIdx.x;
    int idx = blockIdx.x * 256 + tid;
    int v = (idx < n) ? cntcur[idx] : 0;
    sd[tid] = v;
    __syncthreads();
#pragma unroll
    for (int off = 1; off < 256; off <<= 1) {
        int t = (tid >= off) ? sd[tid - off] : 0;
        __syncthreads();
        sd[tid] += t;
        __syncthreads();
    }
    if (idx < n) {
        int ex = boffs[blockIdx.x] + sd[tid] - v;
        offs[idx] = ex;
        cntcur[idx] = ex;  // cursor for fill pass
    }
    if (idx == 0) offs[n] = total;
}

__global__ void fill_kernel(const int* __restrict__ src, const int* __restrict__ dst,
                            const float* __restrict__ el, int* __restrict__ cursor,
                            int* __restrict__ srcS, float* __restrict__ basisS, int E) {
    int e = blockIdx.x * 256 + threadIdx.x;
    if (e >= E) return;
    int d = dst[e];
    int pos = atomicAdd(&cursor[d], 1);
    srcS[pos] = src[e];
    float2 xy = *(const float2*)(el + 2 * (size_t)e);
    float4 b0, b1;
    b0.x = 1.0f; b0.y = __sinf(PI_F * xy.x); b0.z = __cosf(PI_F * xy.x); b0.w = __sinf(2.0f * PI_F * xy.x);
    b1.x = 1.0f; b1.y = __sinf(PI_F * xy.y); b1.z = __cosf(PI_F * xy.y); b1.w = __sinf(2.0f * PI_F * xy.y);
    float4* bp = (float4*)(basisS + (size_t)pos * 8);
    bp[0] = b0;
    bp[1] = b1;
}

// ---------------- W prep: convert f32 W[k][64] -> bf16 Wt[o][K] (transposed) ----------------

__global__ void prep_w_kernel(const float* __restrict__ W, __hip_bfloat16* __restrict__ Wt, int K) {
    int i = blockIdx.x * 256 + threadIdx.x;
    if (i >= K * 64) return;
    int k = i >> 6, o = i & 63;
    Wt[(size_t)o * K + k] = __float2bfloat16(W[i]);
}

// ---------------- per-layer: edge aggregation into A[n, 8*F] (bf16 out) ----------------

template <int F>
__global__ __launch_bounds__(256) void agg_kernel(const float* __restrict__ h,
                                                  const int* __restrict__ srcS,
                                                  const float* __restrict__ basisS,
                                                  const int* __restrict__ offs,
                                                  __hip_bfloat16* __restrict__ A, int nN) {
    constexpr int SLOTS = 64 / F;
    int wid = (blockIdx.x * 256 + threadIdx.x) >> 6;
    int lane = threadIdx.x & 63;
    if (wid >= nN) return;
    int f = lane & (F - 1);
    int slot = lane / F;
    int start = offs[wid], end = offs[wid + 1];
    float a0 = 0, a1 = 0, a2 = 0, a3 = 0, a4 = 0, a5 = 0, a6 = 0, a7 = 0;
    const float4* bp = (const float4*)basisS;
    int j = start + slot;
    for (; j + 3 * SLOTS < end; j += 4 * SLOTS) {
        int j0 = j, j1 = j + SLOTS, j2 = j + 2 * SLOTS, j3 = j + 3 * SLOTS;
        int s0 = srcS[j0], s1 = srcS[j1], s2 = srcS[j2], s3 = srcS[j3];
        float h0 = h[(size_t)s0 * F + f];
        float h1 = h[(size_t)s1 * F + f];
        float h2 = h[(size_t)s2 * F + f];
        float h3 = h[(size_t)s3 * F + f];
        float4 c00 = bp[2 * j0], c01 = bp[2 * j0 + 1];
        float4 c10 = bp[2 * j1], c11 = bp[2 * j1 + 1];
        float4 c20 = bp[2 * j2], c21 = bp[2 * j2 + 1];
        float4 c30 = bp[2 * j3], c31 = bp[2 * j3 + 1];
        a0 += c00.x * h0; a1 += c00.y * h0; a2 += c00.z * h0; a3 += c00.w * h0;
        a4 += c01.x * h0; a5 += c01.y * h0; a6 += c01.z * h0; a7 += c01.w * h0;
        a0 += c10.x * h1; a1 += c10.y * h1; a2 += c10.z * h1; a3 += c10.w * h1;
        a4 += c11.x * h1; a5 += c11.y * h1; a6 += c11.z * h1; a7 += c11.w * h1;
        a0 += c20.x * h2; a1 += c20.y * h2; a2 += c20.z * h2; a3 += c20.w * h2;
        a4 += c21.x * h2; a5 += c21.y * h2; a6 += c21.z * h2; a7 += c21.w * h2;
        a0 += c30.x * h3; a1 += c30.y * h3; a2 += c30.z * h3; a3 += c30.w * h3;
        a4 += c31.x * h3; a5 += c31.y * h3; a6 += c31.z * h3; a7 += c31.w * h3;
    }
    for (; j < end; j += SLOTS) {
        int s = srcS[j];
        float hv = h[(size_t)s * F + f];
        float4 b0 = bp[2 * j], b1 = bp[2 * j + 1];
        a0 += b0.x * hv; a1 += b0.y * hv; a2 += b0.z * hv; a3 += b0.w * hv;
        a4 += b1.x * hv; a5 += b1.y * hv; a6 += b1.z * hv; a7 += b1.w * hv;
    }
    if (SLOTS > 1) {
#pragma unroll
        for (int m = F; m < 64; m <<= 1) {
            a0 += __shfl_xor(a0, m, 64); a1 += __shfl_xor(a1, m, 64);
            a2 += __shfl_xor(a2, m, 64); a3 += __shfl_xor(a3, m, 64);
            a4 += __shfl_xor(a4, m, 64); a5 += __shfl_xor(a5, m, 64);
            a6 += __shfl_xor(a6, m, 64); a7 += __shfl_xor(a7, m, 64);
        }
    }
    if (slot == 0) {
        __hip_bfloat16* Ar = A + (size_t)wid * (8 * F);
        Ar[0 * F + f] = __float2bfloat16(a0); Ar[1 * F + f] = __float2bfloat16(a1);
        Ar[2 * F + f] = __float2bfloat16(a2); Ar[3 * F + f] = __float2bfloat16(a3);
        Ar[4 * F + f] = __float2bfloat16(a4); Ar[5 * F + f] = __float2bfloat16(a5);
        Ar[6 * F + f] = __float2bfloat16(a6); Ar[7 * F + f] = __float2bfloat16(a7);
    }
}

// ---------------- fused final layer: agg (F=64) + [512x2] contraction + scale (f32) ----------------

__global__ __launch_bounds__(256) void agg_out_kernel(const float* __restrict__ h,
                                                      const int* __restrict__ srcS,
                                                      const float* __restrict__ basisS,
                                                      const int* __restrict__ offs,
                                                      const float* __restrict__ W3,
                                                      float* __restrict__ out, int nN) {
    int wid = (blockIdx.x * 256 + threadIdx.x) >> 6;
    int lane = threadIdx.x & 63;
    if (wid >= nN) return;
    int start = offs[wid], end = offs[wid + 1];
    float a0 = 0, a1 = 0, a2 = 0, a3 = 0, a4 = 0, a5 = 0, a6 = 0, a7 = 0;
    const float4* bp = (const float4*)basisS;
    int j = start;
    for (; j + 3 < end; j += 4) {
        int s0 = srcS[j], s1 = srcS[j + 1], s2 = srcS[j + 2], s3 = srcS[j + 3];
        float h0 = h[(size_t)s0 * 64 + lane];
        float h1 = h[(size_t)s1 * 64 + lane];
        float h2 = h[(size_t)s2 * 64 + lane];
        float h3 = h[(size_t)s3 * 64 + lane];
        float4 c00 = bp[2 * j], c01 = bp[2 * j + 1];
        float4 c10 = bp[2 * j + 2], c11 = bp[2 * j + 3];
        float4 c20 = bp[2 * j + 4], c21 = bp[2 * j + 5];
        float4 c30 = bp[2 * j + 6], c31 = bp[2 * j + 7];
        a0 += c00.x * h0; a1 += c00.y * h0; a2 += c00.z * h0; a3 += c00.w * h0;
        a4 += c01.x * h0; a5 += c01.y * h0; a6 += c01.z * h0; a7 += c01.w * h0;
        a0 += c10.x * h1; a1 += c10.y * h1; a2 += c10.z * h1; a3 += c10.w * h1;
        a4 += c11.x * h1; a5 += c11.y * h1; a6 += c11.z * h1; a7 += c11.w * h1;
        a0 += c20.x * h2; a1 += c20.y * h2; a2 += c20.z * h2; a3 += c20.w * h2;
        a4 += c21.x * h2; a5 += c21.y * h2; a6 += c21.z * h2; a7 += c21.w * h2;
        a0 += c30.x * h3; a1 += c30.y * h3; a2 += c30.z * h3; a3 += c30.w * h3;
        a4 += c31.x * h3; a5 += c31.y * h3; a6 += c31.z * h3; a7 += c31.w * h3;
    }
    for (; j < end; j++) {
        int s = srcS[j];
        float hv = h[(size_t)s * 64 + lane];
        float4 b0 = bp[2 * j], b1 = bp[2 * j + 1];
        a0 += b0.x * hv; a1 += b0.y * hv; a2 += b0.z * hv; a3 += b0.w * hv;
        a4 += b1.x * hv; a5 += b1.y * hv; a6 += b1.z * hv; a7 += b1.w * hv;
    }
    float o0 = 0, o1 = 0;
    float aa[8] = {a0, a1, a2, a3, a4, a5, a6, a7};
#pragma unroll
    for (int b = 0; b < 8; b++) {
        float2 w = *(const float2*)&W3[(size_t)(b * 64 + lane) * 2];
        o0 += aa[b] * w.x;
        o1 += aa[b] * w.y;
    }
#pragma unroll
    for (int m = 1; m < 64; m <<= 1) {
        o0 += __shfl_xor(o0, m, 64);
        o1 += __shfl_xor(o1, m, 64);
    }
    if (lane == 0) {
        out[(size_t)wid * 2 + 0] = o0 * (1.0f / 128.0f);
        out[(size_t)wid * 2 + 1] = o1 * (1.0f / 128.0f);
    }
}

// ---------------- MFMA GEMM: Hout[n, 0..63] = act(A[n, :K] @ Wt^T) ----------------
// A: [nN][K] bf16 row-major. Wt: [64][K] bf16 (output-major). No LDS.
// Block = 4 waves; wave w covers rows [blk*64 + w*16, +16), all 64 cols.
// Frags (16x16x32 bf16): A/B lane mapping m/n = lane&15, k = (lane>>4)*8 + j.
// C/D: col = lane&15, row = (lane>>4)*4 + reg  [verified m89].

template <int K, bool RELU>
__global__ __launch_bounds__(256) void gemm_mfma_kernel(const __hip_bfloat16* __restrict__ A,
                                                        const __hip_bfloat16* __restrict__ Wt,
                                                        float* __restrict__ Hout, int nN) {
    int wave = threadIdx.x >> 6;
    int lane = threadIdx.x & 63;
    int m16 = lane & 15;
    int kg = lane >> 4;  // 0..3
    int arow = blockIdx.x * 64 + wave * 16 + m16;
    bool rowok = arow < nN;
    const short* Ap = (const short*)A;
    const short* Wp = (const short*)Wt;
    size_t abase = (size_t)arow * K + kg * 8;
    size_t wb0 = (size_t)(0 * 16 + m16) * K + kg * 8;
    size_t wb1 = (size_t)(1 * 16 + m16) * K + kg * 8;
    size_t wb2 = (size_t)(2 * 16 + m16) * K + kg * 8;
    size_t wb3 = (size_t)(3 * 16 + m16) * K + kg * 8;
    f32x4 acc0 = {0.f, 0.f, 0.f, 0.f};
    f32x4 acc1 = {0.f, 0.f, 0.f, 0.f};
    f32x4 acc2 = {0.f, 0.f, 0.f, 0.f};
    f32x4 acc3 = {0.f, 0.f, 0.f, 0.f};
#pragma unroll 4
    for (int kc = 0; kc < K; kc += 32) {
        bf16x8 af = {};
        if (rowok) af = *(const bf16x8*)(Ap + abase + kc);
        bf16x8 b0 = *(const bf16x8*)(Wp + wb0 + kc);
        bf16x8 b1 = *(const bf16x8*)(Wp + wb1 + kc);
        bf16x8 b2 = *(const bf16x8*)(Wp + wb2 + kc);
        bf16x8 b3 = *(const bf16x8*)(Wp + wb3 + kc);
        acc0 = __builtin_amdgcn_mfma_f32_16x16x32_bf16(af, b0, acc0, 0, 0, 0);
        acc1 = __builtin_amdgcn_mfma_f32_16x16x32_bf16(af, b1, acc1, 0, 0, 0);
        acc2 = __builtin_amdgcn_mfma_f32_16x16x32_bf16(af, b2, acc2, 0, 0, 0);
        acc3 = __builtin_amdgcn_mfma_f32_16x16x32_bf16(af, b3, acc3, 0, 0, 0);
    }
    int orow0 = blockIdx.x * 64 + wave * 16 + kg * 4;
#pragma unroll
    for (int r = 0; r < 4; r++) {
        int row = orow0 + r;
        if (row < nN) {
            float v0 = acc0[r], v1 = acc1[r], v2 = acc2[r], v3 = acc3[r];
            if (RELU) {
                v0 = fmaxf(v0, 0.0f); v1 = fmaxf(v1, 0.0f);
                v2 = fmaxf(v2, 0.0f); v3 = fmaxf(v3, 0.0f);
            }
            float* Hr = Hout + (size_t)row * 64;
            Hr[0 * 16 + m16] = v0;
            Hr[1 * 16 + m16] = v1;
            Hr[2 * 16 + m16] = v2;
            Hr[3 * 16 + m16] = v3;
        }
    }
}

// ---------------- launch ----------------

extern "C" void kernel_launch(void* const* d_in, const int* in_sizes, int n_in,
                              void* d_out, int out_size, void* d_ws, size_t ws_size,
                              hipStream_t stream) {
    const float* x  = (const float*)d_in[0];
    const int*   ei = (const int*)d_in[1];
    const float* el = (const float*)d_in[2];
    const float* W0 = (const float*)d_in[3];
    const float* W1 = (const float*)d_in[4];
    const float* W2 = (const float*)d_in[5];
    const float* W3 = (const float*)d_in[6];
    int nN = in_sizes[0] / 16;
    int E  = in_sizes[1] / 2;
    const int* src = ei;
    const int* dst = ei + E;

    char* ws = (char*)d_ws;
    size_t off = 0;
    auto alloc = [&](size_t bytes) -> void* {
        void* p = ws + off;
        off = (off + bytes + 255) & ~(size_t)255;
        return p;
    };
    int nsb = (nN + 255) / 256;  // scan blocks (must be <= 256)
    int*   cntcur = (int*)alloc((size_t)(nN + 1) * 4);
    int*   offs   = (int*)alloc((size_t)(nN + 1) * 4);
    int*   bsum   = (int*)alloc((size_t)nsb * 4);
    int*   boffs  = (int*)alloc((size_t)nsb * 4);
    int*   srcS   = (int*)alloc((size_t)E * 4);
    float* basisS = (float*)alloc((size_t)E * 8 * 4);
    __hip_bfloat16* Ab  = (__hip_bfloat16*)alloc((size_t)nN * 512 * 2);
    __hip_bfloat16* Wt0 = (__hip_bfloat16*)alloc((size_t)64 * 128 * 2);
    __hip_bfloat16* Wt1 = (__hip_bfloat16*)alloc((size_t)64 * 512 * 2);
    __hip_bfloat16* Wt2 = (__hip_bfloat16*)alloc((size_t)64 * 512 * 2);
    float* hA     = (float*)alloc((size_t)nN * 64 * 4);
    float* hB     = (float*)alloc((size_t)nN * 64 * 4);
    (void)ws_size;

    hipMemsetAsync(cntcur, 0, (size_t)nN * 4, stream);
    int eb = (E + 255) / 256;
    count_kernel<<<eb, 256, 0, stream>>>(dst, cntcur, E);
    scan_reduce_kernel<<<nsb, 256, 0, stream>>>(cntcur, bsum, nN);
    scan_top_kernel<<<1, 256, 0, stream>>>(bsum, boffs, nsb);
    scan_apply_kernel<<<nsb, 256, 0, stream>>>(cntcur, offs, boffs, nN, E);
    fill_kernel<<<eb, 256, 0, stream>>>(src, dst, el, cntcur, srcS, basisS, E);

    // W conversions (independent of binning; tiny)
    prep_w_kernel<<<(128 * 64 + 255) / 256, 256, 0, stream>>>(W0, Wt0, 128);
    prep_w_kernel<<<(512 * 64 + 255) / 256, 256, 0, stream>>>(W1, Wt1, 512);
    prep_w_kernel<<<(512 * 64 + 255) / 256, 256, 0, stream>>>(W2, Wt2, 512);

    int nb = (nN + 3) / 4;    // wave-per-node kernels
    int gb = (nN + 63) / 64;  // gemm tiles

    // layer 0: in=16 -> 64
    agg_kernel<16><<<nb, 256, 0, stream>>>(x, srcS, basisS, offs, Ab, nN);
    gemm_mfma_kernel<128, true><<<gb, 256, 0, stream>>>(Ab, Wt0, hA, nN);
    // layer 1: 64 -> 64
    agg_kernel<64><<<nb, 256, 0, stream>>>(hA, srcS, basisS, offs, Ab, nN);
    gemm_mfma_kernel<512, true><<<gb, 256, 0, stream>>>(Ab, Wt1, hB, nN);
    // layer 2: 64 -> 64
    agg_kernel<64><<<nb, 256, 0, stream>>>(hB, srcS, basisS, offs, Ab, nN);
    gemm_mfma_kernel<512, true><<<gb, 256, 0, stream>>>(Ab, Wt2, hA, nN);
    // layer 3 fused: agg + [512x2] + scale
    agg_out_kernel<<<nb, 256, 0, stream>>>(hA, srcS, basisS, offs, W3, (float*)d_out, nN);
}

// Round 5
// 509.416 us; speedup vs baseline: 1.6285x; 1.0013x over previous
//
#include <hip/hip_runtime.h>
#include <hip/hip_bf16.h>
#include <math.h>

#define PI_F 3.14159265358979323846f

typedef __attribute__((ext_vector_type(8))) short bf16x8;
typedef __attribute__((ext_vector_type(4))) float f32x4;

// ---------------- binning (counting sort by dst) ----------------

__global__ void count_kernel(const int* __restrict__ dst, int* __restrict__ cnt, int E) {
    int e = blockIdx.x * 256 + threadIdx.x;
    if (e < E) atomicAdd(&cnt[dst[e]], 1);
}

__global__ __launch_bounds__(256) void scan_reduce_kernel(const int* __restrict__ cnt,
                                                          int* __restrict__ bsum, int n) {
    __shared__ int sd[4];
    int idx = blockIdx.x * 256 + threadIdx.x;
    int v = (idx < n) ? cnt[idx] : 0;
    int s = v;
#pragma unroll
    for (int m = 1; m < 64; m <<= 1) s += __shfl_xor(s, m, 64);
    int wave = threadIdx.x >> 6;
    if ((threadIdx.x & 63) == 0) sd[wave] = s;
    __syncthreads();
    if (threadIdx.x == 0) bsum[blockIdx.x] = sd[0] + sd[1] + sd[2] + sd[3];
}

__global__ __launch_bounds__(256) void scan_top_kernel(const int* __restrict__ bsum,
                                                       int* __restrict__ boffs, int nb) {
    __shared__ int sd[256];
    int tid = threadIdx.x;
    int v = (tid < nb) ? bsum[tid] : 0;
    sd[tid] = v;
    __syncthreads();
#pragma unroll
    for (int off = 1; off < 256; off <<= 1) {
        int t = (tid >= off) ? sd[tid - off] : 0;
        __syncthreads();
        sd[tid] += t;
        __syncthreads();
    }
    if (tid < nb) boffs[tid] = sd[tid] - v;  // exclusive
}

__global__ __launch_bounds__(256) void scan_apply_kernel(int* __restrict__ cntcur,
                                                         int* __restrict__ offs,
                                                         const int* __restrict__ boffs,
                                                         int n, int total) {
    __shared__ int sd[256];
    int tid = threadIdx.x;
    int idx = blockIdx.x * 256 + tid;
    int v = (idx < n) ? cntcur[idx] : 0;
    sd[tid] = v;
    __syncthreads();
#pragma unroll
    for (int off = 1; off < 256; off <<= 1) {
        int t = (tid >= off) ? sd[tid - off] : 0;
        __syncthreads();
        sd[tid] += t;
        __syncthreads();
    }
    if (idx < n) {
        int ex = boffs[blockIdx.x] + sd[tid] - v;
        offs[idx] = ex;
        cntcur[idx] = ex;  // cursor for fill pass
    }
    if (idx == 0) offs[n] = total;
}

__global__ void fill_kernel(const int* __restrict__ src, const int* __restrict__ dst,
                            const float* __restrict__ el, int* __restrict__ cursor,
                            int* __restrict__ srcS, float* __restrict__ basisS, int E) {
    int e = blockIdx.x * 256 + threadIdx.x;
    if (e >= E) return;
    int d = dst[e];
    int pos = atomicAdd(&cursor[d], 1);
    srcS[pos] = src[e];
    float2 xy = *(const float2*)(el + 2 * (size_t)e);
    float4 b0, b1;
    b0.x = 1.0f; b0.y = __sinf(PI_F * xy.x); b0.z = __cosf(PI_F * xy.x); b0.w = __sinf(2.0f * PI_F * xy.x);
    b1.x = 1.0f; b1.y = __sinf(PI_F * xy.y); b1.z = __cosf(PI_F * xy.y); b1.w = __sinf(2.0f * PI_F * xy.y);
    float4* bp = (float4*)(basisS + (size_t)pos * 8);
    bp[0] = b0;
    bp[1] = b1;
}

// ---------------- preps ----------------

__global__ void prep_w_kernel(const float* __restrict__ W, __hip_bfloat16* __restrict__ Wt, int K) {
    int i = blockIdx.x * 256 + threadIdx.x;
    if (i >= K * 64) return;
    int k = i >> 6, o = i & 63;
    Wt[(size_t)o * K + k] = __float2bfloat16(W[i]);
}

__global__ void prep_f2b_kernel(const float* __restrict__ in, __hip_bfloat16* __restrict__ out, int n) {
    int i = blockIdx.x * 256 + threadIdx.x;
    if (i < n) out[i] = __float2bfloat16(in[i]);
}

// ---------------- per-layer: edge aggregation into A[n, 8*F] (bf16 in/out, f32 accum) ----------------

template <int F>
__global__ __launch_bounds__(256) void agg_kernel(const __hip_bfloat16* __restrict__ h,
                                                  const int* __restrict__ srcS,
                                                  const float* __restrict__ basisS,
                                                  const int* __restrict__ offs,
                                                  __hip_bfloat16* __restrict__ A, int nN) {
    constexpr int SLOTS = 64 / F;
    int wid = (blockIdx.x * 256 + threadIdx.x) >> 6;
    int lane = threadIdx.x & 63;
    if (wid >= nN) return;
    int f = lane & (F - 1);
    int slot = lane / F;
    int start = offs[wid], end = offs[wid + 1];
    float a0 = 0, a1 = 0, a2 = 0, a3 = 0, a4 = 0, a5 = 0, a6 = 0, a7 = 0;
    const float4* bp = (const float4*)basisS;
    int j = start + slot;
    for (; j + 3 * SLOTS < end; j += 4 * SLOTS) {
        int j0 = j, j1 = j + SLOTS, j2 = j + 2 * SLOTS, j3 = j + 3 * SLOTS;
        int s0 = srcS[j0], s1 = srcS[j1], s2 = srcS[j2], s3 = srcS[j3];
        float h0 = __bfloat162float(h[(size_t)s0 * F + f]);
        float h1 = __bfloat162float(h[(size_t)s1 * F + f]);
        float h2 = __bfloat162float(h[(size_t)s2 * F + f]);
        float h3 = __bfloat162float(h[(size_t)s3 * F + f]);
        float4 c00 = bp[2 * j0], c01 = bp[2 * j0 + 1];
        float4 c10 = bp[2 * j1], c11 = bp[2 * j1 + 1];
        float4 c20 = bp[2 * j2], c21 = bp[2 * j2 + 1];
        float4 c30 = bp[2 * j3], c31 = bp[2 * j3 + 1];
        a0 += c00.x * h0; a1 += c00.y * h0; a2 += c00.z * h0; a3 += c00.w * h0;
        a4 += c01.x * h0; a5 += c01.y * h0; a6 += c01.z * h0; a7 += c01.w * h0;
        a0 += c10.x * h1; a1 += c10.y * h1; a2 += c10.z * h1; a3 += c10.w * h1;
        a4 += c11.x * h1; a5 += c11.y * h1; a6 += c11.z * h1; a7 += c11.w * h1;
        a0 += c20.x * h2; a1 += c20.y * h2; a2 += c20.z * h2; a3 += c20.w * h2;
        a4 += c21.x * h2; a5 += c21.y * h2; a6 += c21.z * h2; a7 += c21.w * h2;
        a0 += c30.x * h3; a1 += c30.y * h3; a2 += c30.z * h3; a3 += c30.w * h3;
        a4 += c31.x * h3; a5 += c31.y * h3; a6 += c31.z * h3; a7 += c31.w * h3;
    }
    for (; j < end; j += SLOTS) {
        int s = srcS[j];
        float hv = __bfloat162float(h[(size_t)s * F + f]);
        float4 b0 = bp[2 * j], b1 = bp[2 * j + 1];
        a0 += b0.x * hv; a1 += b0.y * hv; a2 += b0.z * hv; a3 += b0.w * hv;
        a4 += b1.x * hv; a5 += b1.y * hv; a6 += b1.z * hv; a7 += b1.w * hv;
    }
    if (SLOTS > 1) {
#pragma unroll
        for (int m = F; m < 64; m <<= 1) {
            a0 += __shfl_xor(a0, m, 64); a1 += __shfl_xor(a1, m, 64);
            a2 += __shfl_xor(a2, m, 64); a3 += __shfl_xor(a3, m, 64);
            a4 += __shfl_xor(a4, m, 64); a5 += __shfl_xor(a5, m, 64);
            a6 += __shfl_xor(a6, m, 64); a7 += __shfl_xor(a7, m, 64);
        }
    }
    if (slot == 0) {
        __hip_bfloat16* Ar = A + (size_t)wid * (8 * F);
        Ar[0 * F + f] = __float2bfloat16(a0); Ar[1 * F + f] = __float2bfloat16(a1);
        Ar[2 * F + f] = __float2bfloat16(a2); Ar[3 * F + f] = __float2bfloat16(a3);
        Ar[4 * F + f] = __float2bfloat16(a4); Ar[5 * F + f] = __float2bfloat16(a5);
        Ar[6 * F + f] = __float2bfloat16(a6); Ar[7 * F + f] = __float2bfloat16(a7);
    }
}

// ---------------- fused final layer: agg (F=64, bf16 h) + [512x2] contraction + scale ----------------

__global__ __launch_bounds__(256) void agg_out_kernel(const __hip_bfloat16* __restrict__ h,
                                                      const int* __restrict__ srcS,
                                                      const float* __restrict__ basisS,
                                                      const int* __restrict__ offs,
                                                      const float* __restrict__ W3,
                                                      float* __restrict__ out, int nN) {
    int wid = (blockIdx.x * 256 + threadIdx.x) >> 6;
    int lane = threadIdx.x & 63;
    if (wid >= nN) return;
    int start = offs[wid], end = offs[wid + 1];
    float a0 = 0, a1 = 0, a2 = 0, a3 = 0, a4 = 0, a5 = 0, a6 = 0, a7 = 0;
    const float4* bp = (const float4*)basisS;
    int j = start;
    for (; j + 3 < end; j += 4) {
        int s0 = srcS[j], s1 = srcS[j + 1], s2 = srcS[j + 2], s3 = srcS[j + 3];
        float h0 = __bfloat162float(h[(size_t)s0 * 64 + lane]);
        float h1 = __bfloat162float(h[(size_t)s1 * 64 + lane]);
        float h2 = __bfloat162float(h[(size_t)s2 * 64 + lane]);
        float h3 = __bfloat162float(h[(size_t)s3 * 64 + lane]);
        float4 c00 = bp[2 * j], c01 = bp[2 * j + 1];
        float4 c10 = bp[2 * j + 2], c11 = bp[2 * j + 3];
        float4 c20 = bp[2 * j + 4], c21 = bp[2 * j + 5];
        float4 c30 = bp[2 * j + 6], c31 = bp[2 * j + 7];
        a0 += c00.x * h0; a1 += c00.y * h0; a2 += c00.z * h0; a3 += c00.w * h0;
        a4 += c01.x * h0; a5 += c01.y * h0; a6 += c01.z * h0; a7 += c01.w * h0;
        a0 += c10.x * h1; a1 += c10.y * h1; a2 += c10.z * h1; a3 += c10.w * h1;
        a4 += c11.x * h1; a5 += c11.y * h1; a6 += c11.z * h1; a7 += c11.w * h1;
        a0 += c20.x * h2; a1 += c20.y * h2; a2 += c20.z * h2; a3 += c20.w * h2;
        a4 += c21.x * h2; a5 += c21.y * h2; a6 += c21.z * h2; a7 += c21.w * h2;
        a0 += c30.x * h3; a1 += c30.y * h3; a2 += c30.z * h3; a3 += c30.w * h3;
        a4 += c31.x * h3; a5 += c31.y * h3; a6 += c31.z * h3; a7 += c31.w * h3;
    }
    for (; j < end; j++) {
        int s = srcS[j];
        float hv = __bfloat162float(h[(size_t)s * 64 + lane]);
        float4 b0 = bp[2 * j], b1 = bp[2 * j + 1];
        a0 += b0.x * hv; a1 += b0.y * hv; a2 += b0.z * hv; a3 += b0.w * hv;
        a4 += b1.x * hv; a5 += b1.y * hv; a6 += b1.z * hv; a7 += b1.w * hv;
    }
    float o0 = 0, o1 = 0;
    float aa[8] = {a0, a1, a2, a3, a4, a5, a6, a7};
#pragma unroll
    for (int b = 0; b < 8; b++) {
        float2 w = *(const float2*)&W3[(size_t)(b * 64 + lane) * 2];
        o0 += aa[b] * w.x;
        o1 += aa[b] * w.y;
    }
#pragma unroll
    for (int m = 1; m < 64; m <<= 1) {
        o0 += __shfl_xor(o0, m, 64);
        o1 += __shfl_xor(o1, m, 64);
    }
    if (lane == 0) {
        out[(size_t)wid * 2 + 0] = o0 * (1.0f / 128.0f);
        out[(size_t)wid * 2 + 1] = o1 * (1.0f / 128.0f);
    }
}

// ---------------- MFMA GEMM: Hout[n, 0..63] = relu(A[n, :K] @ Wt^T), bf16 out ----------------
// A: [nN][K] bf16 row-major. Wt: [64][K] bf16 (output-major). No LDS.
// Frags (16x16x32 bf16): A/B lane mapping m/n = lane&15, k = (lane>>4)*8 + j.
// C/D: col = lane&15, row = (lane>>4)*4 + reg  [verified m89].

template <int K, bool RELU>
__global__ __launch_bounds__(256) void gemm_mfma_kernel(const __hip_bfloat16* __restrict__ A,
                                                        const __hip_bfloat16* __restrict__ Wt,
                                                        __hip_bfloat16* __restrict__ Hout, int nN) {
    int wave = threadIdx.x >> 6;
    int lane = threadIdx.x & 63;
    int m16 = lane & 15;
    int kg = lane >> 4;  // 0..3
    int arow = blockIdx.x * 64 + wave * 16 + m16;
    bool rowok = arow < nN;
    const short* Ap = (const short*)A;
    const short* Wp = (const short*)Wt;
    size_t abase = (size_t)arow * K + kg * 8;
    size_t wb0 = (size_t)(0 * 16 + m16) * K + kg * 8;
    size_t wb1 = (size_t)(1 * 16 + m16) * K + kg * 8;
    size_t wb2 = (size_t)(2 * 16 + m16) * K + kg * 8;
    size_t wb3 = (size_t)(3 * 16 + m16) * K + kg * 8;
    f32x4 acc0 = {0.f, 0.f, 0.f, 0.f};
    f32x4 acc1 = {0.f, 0.f, 0.f, 0.f};
    f32x4 acc2 = {0.f, 0.f, 0.f, 0.f};
    f32x4 acc3 = {0.f, 0.f, 0.f, 0.f};
#pragma unroll 4
    for (int kc = 0; kc < K; kc += 32) {
        bf16x8 af = {};
        if (rowok) af = *(const bf16x8*)(Ap + abase + kc);
        bf16x8 b0 = *(const bf16x8*)(Wp + wb0 + kc);
        bf16x8 b1 = *(const bf16x8*)(Wp + wb1 + kc);
        bf16x8 b2 = *(const bf16x8*)(Wp + wb2 + kc);
        bf16x8 b3 = *(const bf16x8*)(Wp + wb3 + kc);
        acc0 = __builtin_amdgcn_mfma_f32_16x16x32_bf16(af, b0, acc0, 0, 0, 0);
        acc1 = __builtin_amdgcn_mfma_f32_16x16x32_bf16(af, b1, acc1, 0, 0, 0);
        acc2 = __builtin_amdgcn_mfma_f32_16x16x32_bf16(af, b2, acc2, 0, 0, 0);
        acc3 = __builtin_amdgcn_mfma_f32_16x16x32_bf16(af, b3, acc3, 0, 0, 0);
    }
    int orow0 = blockIdx.x * 64 + wave * 16 + kg * 4;
#pragma unroll
    for (int r = 0; r < 4; r++) {
        int row = orow0 + r;
        if (row < nN) {
            float v0 = acc0[r], v1 = acc1[r], v2 = acc2[r], v3 = acc3[r];
            if (RELU) {
                v0 = fmaxf(v0, 0.0f); v1 = fmaxf(v1, 0.0f);
                v2 = fmaxf(v2, 0.0f); v3 = fmaxf(v3, 0.0f);
            }
            __hip_bfloat16* Hr = Hout + (size_t)row * 64;
            Hr[0 * 16 + m16] = __float2bfloat16(v0);
            Hr[1 * 16 + m16] = __float2bfloat16(v1);
            Hr[2 * 16 + m16] = __float2bfloat16(v2);
            Hr[3 * 16 + m16] = __float2bfloat16(v3);
        }
    }
}

// ---------------- launch ----------------

extern "C" void kernel_launch(void* const* d_in, const int* in_sizes, int n_in,
                              void* d_out, int out_size, void* d_ws, size_t ws_size,
                              hipStream_t stream) {
    const float* x  = (const float*)d_in[0];
    const int*   ei = (const int*)d_in[1];
    const float* el = (const float*)d_in[2];
    const float* W0 = (const float*)d_in[3];
    const float* W1 = (const float*)d_in[4];
    const float* W2 = (const float*)d_in[5];
    const float* W3 = (const float*)d_in[6];
    int nN = in_sizes[0] / 16;
    int E  = in_sizes[1] / 2;
    const int* src = ei;
    const int* dst = ei + E;

    char* ws = (char*)d_ws;
    size_t off = 0;
    auto alloc = [&](size_t bytes) -> void* {
        void* p = ws + off;
        off = (off + bytes + 255) & ~(size_t)255;
        return p;
    };
    int nsb = (nN + 255) / 256;  // scan blocks (must be <= 256)
    int*   cntcur = (int*)alloc((size_t)(nN + 1) * 4);
    int*   offs   = (int*)alloc((size_t)(nN + 1) * 4);
    int*   bsum   = (int*)alloc((size_t)nsb * 4);
    int*   boffs  = (int*)alloc((size_t)nsb * 4);
    int*   srcS   = (int*)alloc((size_t)E * 4);
    float* basisS = (float*)alloc((size_t)E * 8 * 4);
    __hip_bfloat16* Ab  = (__hip_bfloat16*)alloc((size_t)nN * 512 * 2);
    __hip_bfloat16* Wt0 = (__hip_bfloat16*)alloc((size_t)64 * 128 * 2);
    __hip_bfloat16* Wt1 = (__hip_bfloat16*)alloc((size_t)64 * 512 * 2);
    __hip_bfloat16* Wt2 = (__hip_bfloat16*)alloc((size_t)64 * 512 * 2);
    __hip_bfloat16* xb  = (__hip_bfloat16*)alloc((size_t)nN * 16 * 2);
    __hip_bfloat16* hA  = (__hip_bfloat16*)alloc((size_t)nN * 64 * 2);
    __hip_bfloat16* hB  = (__hip_bfloat16*)alloc((size_t)nN * 64 * 2);
    (void)ws_size;

    hipMemsetAsync(cntcur, 0, (size_t)nN * 4, stream);
    int eb = (E + 255) / 256;
    count_kernel<<<eb, 256, 0, stream>>>(dst, cntcur, E);
    scan_reduce_kernel<<<nsb, 256, 0, stream>>>(cntcur, bsum, nN);
    scan_top_kernel<<<1, 256, 0, stream>>>(bsum, boffs, nsb);
    scan_apply_kernel<<<nsb, 256, 0, stream>>>(cntcur, offs, boffs, nN, E);
    fill_kernel<<<eb, 256, 0, stream>>>(src, dst, el, cntcur, srcS, basisS, E);

    // preps (independent of binning; tiny)
    prep_w_kernel<<<(128 * 64 + 255) / 256, 256, 0, stream>>>(W0, Wt0, 128);
    prep_w_kernel<<<(512 * 64 + 255) / 256, 256, 0, stream>>>(W1, Wt1, 512);
    prep_w_kernel<<<(512 * 64 + 255) / 256, 256, 0, stream>>>(W2, Wt2, 512);
    prep_f2b_kernel<<<(nN * 16 + 255) / 256, 256, 0, stream>>>(x, xb, nN * 16);

    int nb = (nN + 3) / 4;    // wave-per-node kernels
    int gb = (nN + 63) / 64;  // gemm tiles

    // layer 0: in=16 -> 64
    agg_kernel<16><<<nb, 256, 0, stream>>>(xb, srcS, basisS, offs, Ab, nN);
    gemm_mfma_kernel<128, true><<<gb, 256, 0, stream>>>(Ab, Wt0, hA, nN);
    // layer 1: 64 -> 64
    agg_kernel<64><<<nb, 256, 0, stream>>>(hA, srcS, basisS, offs, Ab, nN);
    gemm_mfma_kernel<512, true><<<gb, 256, 0, stream>>>(Ab, Wt1, hB, nN);
    // layer 2: 64 -> 64
    agg_kernel<64><<<nb, 256, 0, stream>>>(hB, srcS, basisS, offs, Ab, nN);
    gemm_mfma_kernel<512, true><<<gb, 256, 0, stream>>>(Ab, Wt2, hA, nN);
    // layer 3 fused: agg + [512x2] + scale
    agg_out_kernel<<<nb, 256, 0, stream>>>(hA, srcS, basisS, offs, W3, (float*)d_out, nN);
}

// Round 6
// 508.867 us; speedup vs baseline: 1.6302x; 1.0011x over previous
//
#include <hip/hip_runtime.h>
#include <hip/hip_bf16.h>
#include <math.h>

#define PI_F 3.14159265358979323846f

typedef __attribute__((ext_vector_type(8))) short bf16x8;
typedef __attribute__((ext_vector_type(4))) float f32x4;

// ---------------- binning (counting sort by dst) ----------------

__global__ void count_kernel(const int* __restrict__ dst, int* __restrict__ cnt, int E) {
    int e = blockIdx.x * 256 + threadIdx.x;
    if (e < E) atomicAdd(&cnt[dst[e]], 1);
}

__global__ __launch_bounds__(256) void scan_reduce_kernel(const int* __restrict__ cnt,
                                                          int* __restrict__ bsum, int n) {
    __shared__ int sd[4];
    int idx = blockIdx.x * 256 + threadIdx.x;
    int v = (idx < n) ? cnt[idx] : 0;
    int s = v;
#pragma unroll
    for (int m = 1; m < 64; m <<= 1) s += __shfl_xor(s, m, 64);
    int wave = threadIdx.x >> 6;
    if ((threadIdx.x & 63) == 0) sd[wave] = s;
    __syncthreads();
    if (threadIdx.x == 0) bsum[blockIdx.x] = sd[0] + sd[1] + sd[2] + sd[3];
}

__global__ __launch_bounds__(256) void scan_top_kernel(const int* __restrict__ bsum,
                                                       int* __restrict__ boffs, int nb) {
    __shared__ int sd[256];
    int tid = threadIdx.x;
    int v = (tid < nb) ? bsum[tid] : 0;
    sd[tid] = v;
    __syncthreads();
#pragma unroll
    for (int off = 1; off < 256; off <<= 1) {
        int t = (tid >= off) ? sd[tid - off] : 0;
        __syncthreads();
        sd[tid] += t;
        __syncthreads();
    }
    if (tid < nb) boffs[tid] = sd[tid] - v;  // exclusive
}

__global__ __launch_bounds__(256) void scan_apply_kernel(int* __restrict__ cntcur,
                                                         int* __restrict__ offs,
                                                         const int* __restrict__ boffs,
                                                         int n, int total) {
    __shared__ int sd[256];
    int tid = threadIdx.x;
    int idx = blockIdx.x * 256 + tid;
    int v = (idx < n) ? cntcur[idx] : 0;
    sd[tid] = v;
    __syncthreads();
#pragma unroll
    for (int off = 1; off < 256; off <<= 1) {
        int t = (tid >= off) ? sd[tid - off] : 0;
        __syncthreads();
        sd[tid] += t;
        __syncthreads();
    }
    if (idx < n) {
        int ex = boffs[blockIdx.x] + sd[tid] - v;
        offs[idx] = ex;
        cntcur[idx] = ex;  // cursor for fill pass
    }
    if (idx == 0) offs[n] = total;
}

__global__ void fill_kernel(const int* __restrict__ src, const int* __restrict__ dst,
                            const float* __restrict__ el, int* __restrict__ cursor,
                            int* __restrict__ srcS, float* __restrict__ basisS, int E) {
    int e = blockIdx.x * 256 + threadIdx.x;
    if (e >= E) return;
    int d = dst[e];
    int pos = atomicAdd(&cursor[d], 1);
    srcS[pos] = src[e];
    float2 xy = *(const float2*)(el + 2 * (size_t)e);
    float4 b0, b1;
    b0.x = 1.0f; b0.y = __sinf(PI_F * xy.x); b0.z = __cosf(PI_F * xy.x); b0.w = __sinf(2.0f * PI_F * xy.x);
    b1.x = 1.0f; b1.y = __sinf(PI_F * xy.y); b1.z = __cosf(PI_F * xy.y); b1.w = __sinf(2.0f * PI_F * xy.y);
    float4* bp = (float4*)(basisS + (size_t)pos * 8);
    bp[0] = b0;
    bp[1] = b1;
}

// ---------------- preps ----------------

__global__ void prep_w_kernel(const float* __restrict__ W, __hip_bfloat16* __restrict__ Wt, int K) {
    int i = blockIdx.x * 256 + threadIdx.x;
    if (i >= K * 64) return;
    int k = i >> 6, o = i & 63;
    Wt[(size_t)o * K + k] = __float2bfloat16(W[i]);
}

__global__ void prep_f2b_kernel(const float* __restrict__ in, __hip_bfloat16* __restrict__ out, int n) {
    int i = blockIdx.x * 256 + threadIdx.x;
    if (i < n) out[i] = __float2bfloat16(in[i]);
}

// ---------------- agg for F=64: one wave per node, lane = feature ----------------
// 8-deep MLP batch: all srcS + all gathers issued before any FMA consumes them.

#define EDGE_FMA(Hv, C0, C1)                                                      \
    a0 += (C0).x * (Hv); a1 += (C0).y * (Hv); a2 += (C0).z * (Hv); a3 += (C0).w * (Hv); \
    a4 += (C1).x * (Hv); a5 += (C1).y * (Hv); a6 += (C1).z * (Hv); a7 += (C1).w * (Hv);

template <bool OUT>
__device__ __forceinline__ void agg64_body(const __hip_bfloat16* __restrict__ h,
                                           const int* __restrict__ srcS,
                                           const float* __restrict__ basisS,
                                           int start, int end, int lane,
                                           float& a0, float& a1, float& a2, float& a3,
                                           float& a4, float& a5, float& a6, float& a7) {
    const float4* bp = (const float4*)basisS;
    int j = start;
    for (; j + 7 < end; j += 8) {
        // batch of 8: srcS reads (independent), then 8 gathers (in flight together)
        int s0 = srcS[j + 0], s1 = srcS[j + 1], s2 = srcS[j + 2], s3 = srcS[j + 3];
        int s4 = srcS[j + 4], s5 = srcS[j + 5], s6 = srcS[j + 6], s7 = srcS[j + 7];
        float h0 = __bfloat162float(h[(size_t)s0 * 64 + lane]);
        float h1 = __bfloat162float(h[(size_t)s1 * 64 + lane]);
        float h2 = __bfloat162float(h[(size_t)s2 * 64 + lane]);
        float h3 = __bfloat162float(h[(size_t)s3 * 64 + lane]);
        float h4 = __bfloat162float(h[(size_t)s4 * 64 + lane]);
        float h5 = __bfloat162float(h[(size_t)s5 * 64 + lane]);
        float h6 = __bfloat162float(h[(size_t)s6 * 64 + lane]);
        float h7 = __bfloat162float(h[(size_t)s7 * 64 + lane]);
        // basis consumed pairwise (keeps VGPR pressure low; uniform addresses)
        {
            float4 c00 = bp[2 * (j + 0)], c01 = bp[2 * (j + 0) + 1];
            float4 c10 = bp[2 * (j + 1)], c11 = bp[2 * (j + 1) + 1];
            EDGE_FMA(h0, c00, c01)
            EDGE_FMA(h1, c10, c11)
        }
        {
            float4 c00 = bp[2 * (j + 2)], c01 = bp[2 * (j + 2) + 1];
            float4 c10 = bp[2 * (j + 3)], c11 = bp[2 * (j + 3) + 1];
            EDGE_FMA(h2, c00, c01)
            EDGE_FMA(h3, c10, c11)
        }
        {
            float4 c00 = bp[2 * (j + 4)], c01 = bp[2 * (j + 4) + 1];
            float4 c10 = bp[2 * (j + 5)], c11 = bp[2 * (j + 5) + 1];
            EDGE_FMA(h4, c00, c01)
            EDGE_FMA(h5, c10, c11)
        }
        {
            float4 c00 = bp[2 * (j + 6)], c01 = bp[2 * (j + 6) + 1];
            float4 c10 = bp[2 * (j + 7)], c11 = bp[2 * (j + 7) + 1];
            EDGE_FMA(h6, c00, c01)
            EDGE_FMA(h7, c10, c11)
        }
    }
    for (; j + 3 < end; j += 4) {
        int s0 = srcS[j + 0], s1 = srcS[j + 1], s2 = srcS[j + 2], s3 = srcS[j + 3];
        float h0 = __bfloat162float(h[(size_t)s0 * 64 + lane]);
        float h1 = __bfloat162float(h[(size_t)s1 * 64 + lane]);
        float h2 = __bfloat162float(h[(size_t)s2 * 64 + lane]);
        float h3 = __bfloat162float(h[(size_t)s3 * 64 + lane]);
        float4 c00 = bp[2 * (j + 0)], c01 = bp[2 * (j + 0) + 1];
        float4 c10 = bp[2 * (j + 1)], c11 = bp[2 * (j + 1) + 1];
        float4 c20 = bp[2 * (j + 2)], c21 = bp[2 * (j + 2) + 1];
        float4 c30 = bp[2 * (j + 3)], c31 = bp[2 * (j + 3) + 1];
        EDGE_FMA(h0, c00, c01)
        EDGE_FMA(h1, c10, c11)
        EDGE_FMA(h2, c20, c21)
        EDGE_FMA(h3, c30, c31)
    }
    for (; j < end; j++) {
        int s = srcS[j];
        float hv = __bfloat162float(h[(size_t)s * 64 + lane]);
        float4 b0 = bp[2 * j], b1 = bp[2 * j + 1];
        EDGE_FMA(hv, b0, b1)
    }
}

__global__ __launch_bounds__(256) void agg64_kernel(const __hip_bfloat16* __restrict__ h,
                                                    const int* __restrict__ srcS,
                                                    const float* __restrict__ basisS,
                                                    const int* __restrict__ offs,
                                                    __hip_bfloat16* __restrict__ A, int nN) {
    int wid = (blockIdx.x * 256 + threadIdx.x) >> 6;
    int lane = threadIdx.x & 63;
    if (wid >= nN) return;
    int start = offs[wid], end = offs[wid + 1];
    float a0 = 0, a1 = 0, a2 = 0, a3 = 0, a4 = 0, a5 = 0, a6 = 0, a7 = 0;
    agg64_body<false>(h, srcS, basisS, start, end, lane, a0, a1, a2, a3, a4, a5, a6, a7);
    __hip_bfloat16* Ar = A + (size_t)wid * 512;
    Ar[0 * 64 + lane] = __float2bfloat16(a0); Ar[1 * 64 + lane] = __float2bfloat16(a1);
    Ar[2 * 64 + lane] = __float2bfloat16(a2); Ar[3 * 64 + lane] = __float2bfloat16(a3);
    Ar[4 * 64 + lane] = __float2bfloat16(a4); Ar[5 * 64 + lane] = __float2bfloat16(a5);
    Ar[6 * 64 + lane] = __float2bfloat16(a6); Ar[7 * 64 + lane] = __float2bfloat16(a7);
}

__global__ __launch_bounds__(256) void agg_out_kernel(const __hip_bfloat16* __restrict__ h,
                                                      const int* __restrict__ srcS,
                                                      const float* __restrict__ basisS,
                                                      const int* __restrict__ offs,
                                                      const float* __restrict__ W3,
                                                      float* __restrict__ out, int nN) {
    int wid = (blockIdx.x * 256 + threadIdx.x) >> 6;
    int lane = threadIdx.x & 63;
    if (wid >= nN) return;
    int start = offs[wid], end = offs[wid + 1];
    float a0 = 0, a1 = 0, a2 = 0, a3 = 0, a4 = 0, a5 = 0, a6 = 0, a7 = 0;
    agg64_body<true>(h, srcS, basisS, start, end, lane, a0, a1, a2, a3, a4, a5, a6, a7);
    float o0 = 0, o1 = 0;
    float aa[8] = {a0, a1, a2, a3, a4, a5, a6, a7};
#pragma unroll
    for (int b = 0; b < 8; b++) {
        float2 w = *(const float2*)&W3[(size_t)(b * 64 + lane) * 2];
        o0 += aa[b] * w.x;
        o1 += aa[b] * w.y;
    }
#pragma unroll
    for (int m = 1; m < 64; m <<= 1) {
        o0 += __shfl_xor(o0, m, 64);
        o1 += __shfl_xor(o1, m, 64);
    }
    if (lane == 0) {
        out[(size_t)wid * 2 + 0] = o0 * (1.0f / 128.0f);
        out[(size_t)wid * 2 + 1] = o1 * (1.0f / 128.0f);
    }
}

// ---------------- agg for F=16 (layer 0): lane = (slot, feature), 4 slots ----------------

__global__ __launch_bounds__(256) void agg16_kernel(const __hip_bfloat16* __restrict__ h,
                                                    const int* __restrict__ srcS,
                                                    const float* __restrict__ basisS,
                                                    const int* __restrict__ offs,
                                                    __hip_bfloat16* __restrict__ A, int nN) {
    constexpr int F = 16;
    constexpr int SLOTS = 4;
    int wid = (blockIdx.x * 256 + threadIdx.x) >> 6;
    int lane = threadIdx.x & 63;
    if (wid >= nN) return;
    int f = lane & (F - 1);
    int slot = lane >> 4;
    int start = offs[wid], end = offs[wid + 1];
    float a0 = 0, a1 = 0, a2 = 0, a3 = 0, a4 = 0, a5 = 0, a6 = 0, a7 = 0;
    const float4* bp = (const float4*)basisS;
    int j = start + slot;
    for (; j + 3 * SLOTS < end; j += 4 * SLOTS) {
        int j0 = j, j1 = j + SLOTS, j2 = j + 2 * SLOTS, j3 = j + 3 * SLOTS;
        int s0 = srcS[j0], s1 = srcS[j1], s2 = srcS[j2], s3 = srcS[j3];
        float h0 = __bfloat162float(h[(size_t)s0 * F + f]);
        float h1 = __bfloat162float(h[(size_t)s1 * F + f]);
        float h2 = __bfloat162float(h[(size_t)s2 * F + f]);
        float h3 = __bfloat162float(h[(size_t)s3 * F + f]);
        float4 c00 = bp[2 * j0], c01 = bp[2 * j0 + 1];
        float4 c10 = bp[2 * j1], c11 = bp[2 * j1 + 1];
        float4 c20 = bp[2 * j2], c21 = bp[2 * j2 + 1];
        float4 c30 = bp[2 * j3], c31 = bp[2 * j3 + 1];
        EDGE_FMA(h0, c00, c01)
        EDGE_FMA(h1, c10, c11)
        EDGE_FMA(h2, c20, c21)
        EDGE_FMA(h3, c30, c31)
    }
    for (; j < end; j += SLOTS) {
        int s = srcS[j];
        float hv = __bfloat162float(h[(size_t)s * F + f]);
        float4 b0 = bp[2 * j], b1 = bp[2 * j + 1];
        EDGE_FMA(hv, b0, b1)
    }
#pragma unroll
    for (int m = F; m < 64; m <<= 1) {
        a0 += __shfl_xor(a0, m, 64); a1 += __shfl_xor(a1, m, 64);
        a2 += __shfl_xor(a2, m, 64); a3 += __shfl_xor(a3, m, 64);
        a4 += __shfl_xor(a4, m, 64); a5 += __shfl_xor(a5, m, 64);
        a6 += __shfl_xor(a6, m, 64); a7 += __shfl_xor(a7, m, 64);
    }
    if (slot == 0) {
        __hip_bfloat16* Ar = A + (size_t)wid * (8 * F);
        Ar[0 * F + f] = __float2bfloat16(a0); Ar[1 * F + f] = __float2bfloat16(a1);
        Ar[2 * F + f] = __float2bfloat16(a2); Ar[3 * F + f] = __float2bfloat16(a3);
        Ar[4 * F + f] = __float2bfloat16(a4); Ar[5 * F + f] = __float2bfloat16(a5);
        Ar[6 * F + f] = __float2bfloat16(a6); Ar[7 * F + f] = __float2bfloat16(a7);
    }
}

// ---------------- MFMA GEMM: Hout[n, 0..63] = relu(A[n, :K] @ Wt^T), bf16 out ----------------
// Frags (16x16x32 bf16): A/B lane mapping m/n = lane&15, k = (lane>>4)*8 + j.
// C/D: col = lane&15, row = (lane>>4)*4 + reg  [verified m89].

template <int K, bool RELU>
__global__ __launch_bounds__(256) void gemm_mfma_kernel(const __hip_bfloat16* __restrict__ A,
                                                        const __hip_bfloat16* __restrict__ Wt,
                                                        __hip_bfloat16* __restrict__ Hout, int nN) {
    int wave = threadIdx.x >> 6;
    int lane = threadIdx.x & 63;
    int m16 = lane & 15;
    int kg = lane >> 4;  // 0..3
    int arow = blockIdx.x * 64 + wave * 16 + m16;
    bool rowok = arow < nN;
    const short* Ap = (const short*)A;
    const short* Wp = (const short*)Wt;
    size_t abase = (size_t)arow * K + kg * 8;
    size_t wb0 = (size_t)(0 * 16 + m16) * K + kg * 8;
    size_t wb1 = (size_t)(1 * 16 + m16) * K + kg * 8;
    size_t wb2 = (size_t)(2 * 16 + m16) * K + kg * 8;
    size_t wb3 = (size_t)(3 * 16 + m16) * K + kg * 8;
    f32x4 acc0 = {0.f, 0.f, 0.f, 0.f};
    f32x4 acc1 = {0.f, 0.f, 0.f, 0.f};
    f32x4 acc2 = {0.f, 0.f, 0.f, 0.f};
    f32x4 acc3 = {0.f, 0.f, 0.f, 0.f};
#pragma unroll 4
    for (int kc = 0; kc < K; kc += 32) {
        bf16x8 af = {};
        if (rowok) af = *(const bf16x8*)(Ap + abase + kc);
        bf16x8 b0 = *(const bf16x8*)(Wp + wb0 + kc);
        bf16x8 b1 = *(const bf16x8*)(Wp + wb1 + kc);
        bf16x8 b2 = *(const bf16x8*)(Wp + wb2 + kc);
        bf16x8 b3 = *(const bf16x8*)(Wp + wb3 + kc);
        acc0 = __builtin_amdgcn_mfma_f32_16x16x32_bf16(af, b0, acc0, 0, 0, 0);
        acc1 = __builtin_amdgcn_mfma_f32_16x16x32_bf16(af, b1, acc1, 0, 0, 0);
        acc2 = __builtin_amdgcn_mfma_f32_16x16x32_bf16(af, b2, acc2, 0, 0, 0);
        acc3 = __builtin_amdgcn_mfma_f32_16x16x32_bf16(af, b3, acc3, 0, 0, 0);
    }
    int orow0 = blockIdx.x * 64 + wave * 16 + kg * 4;
#pragma unroll
    for (int r = 0; r < 4; r++) {
        int row = orow0 + r;
        if (row < nN) {
            float v0 = acc0[r], v1 = acc1[r], v2 = acc2[r], v3 = acc3[r];
            if (RELU) {
                v0 = fmaxf(v0, 0.0f); v1 = fmaxf(v1, 0.0f);
                v2 = fmaxf(v2, 0.0f); v3 = fmaxf(v3, 0.0f);
            }
            __hip_bfloat16* Hr = Hout + (size_t)row * 64;
            Hr[0 * 16 + m16] = __float2bfloat16(v0);
            Hr[1 * 16 + m16] = __float2bfloat16(v1);
            Hr[2 * 16 + m16] = __float2bfloat16(v2);
            Hr[3 * 16 + m16] = __float2bfloat16(v3);
        }
    }
}

// ---------------- launch ----------------

extern "C" void kernel_launch(void* const* d_in, const int* in_sizes, int n_in,
                              void* d_out, int out_size, void* d_ws, size_t ws_size,
                              hipStream_t stream) {
    const float* x  = (const float*)d_in[0];
    const int*   ei = (const int*)d_in[1];
    const float* el = (const float*)d_in[2];
    const float* W0 = (const float*)d_in[3];
    const float* W1 = (const float*)d_in[4];
    const float* W2 = (const float*)d_in[5];
    const float* W3 = (const float*)d_in[6];
    int nN = in_sizes[0] / 16;
    int E  = in_sizes[1] / 2;
    const int* src = ei;
    const int* dst = ei + E;

    char* ws = (char*)d_ws;
    size_t off = 0;
    auto alloc = [&](size_t bytes) -> void* {
        void* p = ws + off;
        off = (off + bytes + 255) & ~(size_t)255;
        return p;
    };
    int nsb = (nN + 255) / 256;  // scan blocks (must be <= 256)
    int*   cntcur = (int*)alloc((size_t)(nN + 1) * 4);
    int*   offs   = (int*)alloc((size_t)(nN + 1) * 4);
    int*   bsum   = (int*)alloc((size_t)nsb * 4);
    int*   boffs  = (int*)alloc((size_t)nsb * 4);
    int*   srcS   = (int*)alloc((size_t)E * 4);
    float* basisS = (float*)alloc((size_t)E * 8 * 4);
    __hip_bfloat16* Ab  = (__hip_bfloat16*)alloc((size_t)nN * 512 * 2);
    __hip_bfloat16* Wt0 = (__hip_bfloat16*)alloc((size_t)64 * 128 * 2);
    __hip_bfloat16* Wt1 = (__hip_bfloat16*)alloc((size_t)64 * 512 * 2);
    __hip_bfloat16* Wt2 = (__hip_bfloat16*)alloc((size_t)64 * 512 * 2);
    __hip_bfloat16* xb  = (__hip_bfloat16*)alloc((size_t)nN * 16 * 2);
    __hip_bfloat16* hA  = (__hip_bfloat16*)alloc((size_t)nN * 64 * 2);
    __hip_bfloat16* hB  = (__hip_bfloat16*)alloc((size_t)nN * 64 * 2);
    (void)ws_size;

    hipMemsetAsync(cntcur, 0, (size_t)nN * 4, stream);
    int eb = (E + 255) / 256;
    count_kernel<<<eb, 256, 0, stream>>>(dst, cntcur, E);
    scan_reduce_kernel<<<nsb, 256, 0, stream>>>(cntcur, bsum, nN);
    scan_top_kernel<<<1, 256, 0, stream>>>(bsum, boffs, nsb);
    scan_apply_kernel<<<nsb, 256, 0, stream>>>(cntcur, offs, boffs, nN, E);
    fill_kernel<<<eb, 256, 0, stream>>>(src, dst, el, cntcur, srcS, basisS, E);

    // preps (independent of binning; tiny)
    prep_w_kernel<<<(128 * 64 + 255) / 256, 256, 0, stream>>>(W0, Wt0, 128);
    prep_w_kernel<<<(512 * 64 + 255) / 256, 256, 0, stream>>>(W1, Wt1, 512);
    prep_w_kernel<<<(512 * 64 + 255) / 256, 256, 0, stream>>>(W2, Wt2, 512);
    prep_f2b_kernel<<<(nN * 16 + 255) / 256, 256, 0, stream>>>(x, xb, nN * 16);

    int nb = (nN + 3) / 4;    // wave-per-node kernels
    int gb = (nN + 63) / 64;  // gemm tiles

    // layer 0: in=16 -> 64
    agg16_kernel<<<nb, 256, 0, stream>>>(xb, srcS, basisS, offs, Ab, nN);
    gemm_mfma_kernel<128, true><<<gb, 256, 0, stream>>>(Ab, Wt0, hA, nN);
    // layer 1: 64 -> 64
    agg64_kernel<<<nb, 256, 0, stream>>>(hA, srcS, basisS, offs, Ab, nN);
    gemm_mfma_kernel<512, true><<<gb, 256, 0, stream>>>(Ab, Wt1, hB, nN);
    // layer 2: 64 -> 64
    agg64_kernel<<<nb, 256, 0, stream>>>(hB, srcS, basisS, offs, Ab, nN);
    gemm_mfma_kernel<512, true><<<gb, 256, 0, stream>>>(Ab, Wt2, hA, nN);
    // layer 3 fused: agg + [512x2] + scale
    agg_out_kernel<<<nb, 256, 0, stream>>>(hA, srcS, basisS, offs, W3, (float*)d_out, nN);
}

// Round 7
// 446.192 us; speedup vs baseline: 1.8592x; 1.1405x over previous
//
#include <hip/hip_runtime.h>
#include <hip/hip_bf16.h>
#include <math.h>

#define PI_F 3.14159265358979323846f

typedef __attribute__((ext_vector_type(8))) short bf16x8;
typedef __attribute__((ext_vector_type(4))) float f32x4;
typedef __attribute__((ext_vector_type(4))) unsigned short u16x4;

__device__ __forceinline__ float bf2f(unsigned short u) {
    union { unsigned int i; float f; } v;
    v.i = ((unsigned int)u) << 16;
    return v.f;
}

__device__ __forceinline__ unsigned short f2bf_bits(float f) {
    __hip_bfloat16 b = __float2bfloat16(f);
    unsigned short u;
    __builtin_memcpy(&u, &b, 2);
    return u;
}

// ---------------- binning (counting sort by dst) ----------------

__global__ void count_kernel(const int* __restrict__ dst, int* __restrict__ cnt, int E) {
    int e = blockIdx.x * 256 + threadIdx.x;
    if (e < E) atomicAdd(&cnt[dst[e]], 1);
}

__global__ __launch_bounds__(256) void scan_reduce_kernel(const int* __restrict__ cnt,
                                                          int* __restrict__ bsum, int n) {
    __shared__ int sd[4];
    int idx = blockIdx.x * 256 + threadIdx.x;
    int v = (idx < n) ? cnt[idx] : 0;
    int s = v;
#pragma unroll
    for (int m = 1; m < 64; m <<= 1) s += __shfl_xor(s, m, 64);
    int wave = threadIdx.x >> 6;
    if ((threadIdx.x & 63) == 0) sd[wave] = s;
    __syncthreads();
    if (threadIdx.x == 0) bsum[blockIdx.x] = sd[0] + sd[1] + sd[2] + sd[3];
}

__global__ __launch_bounds__(256) void scan_top_kernel(const int* __restrict__ bsum,
                                                       int* __restrict__ boffs, int nb) {
    __shared__ int sd[256];
    int tid = threadIdx.x;
    int v = (tid < nb) ? bsum[tid] : 0;
    sd[tid] = v;
    __syncthreads();
#pragma unroll
    for (int off = 1; off < 256; off <<= 1) {
        int t = (tid >= off) ? sd[tid - off] : 0;
        __syncthreads();
        sd[tid] += t;
        __syncthreads();
    }
    if (tid < nb) boffs[tid] = sd[tid] - v;  // exclusive
}

__global__ __launch_bounds__(256) void scan_apply_kernel(int* __restrict__ cntcur,
                                                         int* __restrict__ offs,
                                                         const int* __restrict__ boffs,
                                                         int n, int total) {
    __shared__ int sd[256];
    int tid = threadIdx.x;
    int idx = blockIdx.x * 256 + tid;
    int v = (idx < n) ? cntcur[idx] : 0;
    sd[tid] = v;
    __syncthreads();
#pragma unroll
    for (int off = 1; off < 256; off <<= 1) {
        int t = (tid >= off) ? sd[tid - off] : 0;
        __syncthreads();
        sd[tid] += t;
        __syncthreads();
    }
    if (idx < n) {
        int ex = boffs[blockIdx.x] + sd[tid] - v;
        offs[idx] = ex;
        cntcur[idx] = ex;  // cursor for fill pass
    }
    if (idx == 0) offs[n] = total;
}

__global__ void fill_kernel(const int* __restrict__ src, const int* __restrict__ dst,
                            const float* __restrict__ el, int* __restrict__ cursor,
                            int* __restrict__ srcS, float* __restrict__ basisS, int E) {
    int e = blockIdx.x * 256 + threadIdx.x;
    if (e >= E) return;
    int d = dst[e];
    int pos = atomicAdd(&cursor[d], 1);
    srcS[pos] = src[e];
    float2 xy = *(const float2*)(el + 2 * (size_t)e);
    float4 b0, b1;
    b0.x = 1.0f; b0.y = __sinf(PI_F * xy.x); b0.z = __cosf(PI_F * xy.x); b0.w = __sinf(2.0f * PI_F * xy.x);
    b1.x = 1.0f; b1.y = __sinf(PI_F * xy.y); b1.z = __cosf(PI_F * xy.y); b1.w = __sinf(2.0f * PI_F * xy.y);
    float4* bp = (float4*)(basisS + (size_t)pos * 8);
    bp[0] = b0;
    bp[1] = b1;
}

// ---------------- preps ----------------

__global__ void prep_w_kernel(const float* __restrict__ W, __hip_bfloat16* __restrict__ Wt, int K) {
    int i = blockIdx.x * 256 + threadIdx.x;
    if (i >= K * 64) return;
    int k = i >> 6, o = i & 63;
    Wt[(size_t)o * K + k] = __float2bfloat16(W[i]);
}

__global__ void prep_f2b_kernel(const float* __restrict__ in, __hip_bfloat16* __restrict__ out, int n) {
    int i = blockIdx.x * 256 + threadIdx.x;
    if (i < n) out[i] = __float2bfloat16(in[i]);
}

// ---------------- agg F=64: wave per node, lane = (edge-slot eg 0..3, feat-slice fg 0..15) ----------------
// Each wave-instruction gathers 4 edges x 8B (lane loads h[src]*64 + fg*4 .. +3).
// acc[b][c]: basis-term b (0..7) x feature c (fg*4+c). Reduce over eg at the end.

__device__ __forceinline__ void agg64_core(const unsigned short* __restrict__ hp,
                                           const int* __restrict__ srcS,
                                           const float4* __restrict__ bp,
                                           int start, int end, int eg, int fg,
                                           float acc[8][4]) {
    for (int j = start; j < end; j += 8) {
        int e0 = j + eg;
        int e1 = j + 4 + eg;
        int q0 = min(e0, end - 1);
        int q1 = min(e1, end - 1);
        int s0 = srcS[q0];
        int s1 = srcS[q1];
        u16x4 g0 = *(const u16x4*)(hp + (size_t)s0 * 64 + fg * 4);
        u16x4 g1 = *(const u16x4*)(hp + (size_t)s1 * 64 + fg * 4);
        float4 c00 = bp[2 * q0], c01 = bp[2 * q0 + 1];
        float4 c10 = bp[2 * q1], c11 = bp[2 * q1 + 1];
        float h0[4], h1[4];
        h0[0] = bf2f(g0[0]); h0[1] = bf2f(g0[1]); h0[2] = bf2f(g0[2]); h0[3] = bf2f(g0[3]);
        h1[0] = bf2f(g1[0]); h1[1] = bf2f(g1[1]); h1[2] = bf2f(g1[2]); h1[3] = bf2f(g1[3]);
        if (e0 >= end) { h0[0] = 0.f; h0[1] = 0.f; h0[2] = 0.f; h0[3] = 0.f; }
        if (e1 >= end) { h1[0] = 0.f; h1[1] = 0.f; h1[2] = 0.f; h1[3] = 0.f; }
        float bas0[8] = {c00.x, c00.y, c00.z, c00.w, c01.x, c01.y, c01.z, c01.w};
        float bas1[8] = {c10.x, c10.y, c10.z, c10.w, c11.x, c11.y, c11.z, c11.w};
#pragma unroll
        for (int b = 0; b < 8; b++) {
#pragma unroll
            for (int c = 0; c < 4; c++) acc[b][c] += bas0[b] * h0[c];
        }
#pragma unroll
        for (int b = 0; b < 8; b++) {
#pragma unroll
            for (int c = 0; c < 4; c++) acc[b][c] += bas1[b] * h1[c];
        }
    }
}

__global__ __launch_bounds__(256) void agg64_kernel(const __hip_bfloat16* __restrict__ h,
                                                    const int* __restrict__ srcS,
                                                    const float* __restrict__ basisS,
                                                    const int* __restrict__ offs,
                                                    __hip_bfloat16* __restrict__ A, int nN) {
    int wid = (blockIdx.x * 256 + threadIdx.x) >> 6;
    int lane = threadIdx.x & 63;
    if (wid >= nN) return;
    int eg = lane >> 4, fg = lane & 15;
    int start = offs[wid], end = offs[wid + 1];
    float acc[8][4] = {};
    if (start < end)
        agg64_core((const unsigned short*)h, srcS, (const float4*)basisS, start, end, eg, fg, acc);
#pragma unroll
    for (int b = 0; b < 8; b++) {
#pragma unroll
        for (int c = 0; c < 4; c++) {
            float v = acc[b][c];
            v += __shfl_xor(v, 16, 64);
            v += __shfl_xor(v, 32, 64);
            acc[b][c] = v;
        }
    }
    if (eg == 0) {
        unsigned short* Ar = (unsigned short*)A + (size_t)wid * 512;
#pragma unroll
        for (int b = 0; b < 8; b++) {
            u16x4 p;
            p[0] = f2bf_bits(acc[b][0]); p[1] = f2bf_bits(acc[b][1]);
            p[2] = f2bf_bits(acc[b][2]); p[3] = f2bf_bits(acc[b][3]);
            *(u16x4*)(Ar + b * 64 + fg * 4) = p;
        }
    }
}

// fused final layer: agg64 + [512x2] contraction + scale
__global__ __launch_bounds__(256) void agg_out_kernel(const __hip_bfloat16* __restrict__ h,
                                                      const int* __restrict__ srcS,
                                                      const float* __restrict__ basisS,
                                                      const int* __restrict__ offs,
                                                      const float* __restrict__ W3,
                                                      float* __restrict__ out, int nN) {
    int wid = (blockIdx.x * 256 + threadIdx.x) >> 6;
    int lane = threadIdx.x & 63;
    if (wid >= nN) return;
    int eg = lane >> 4, fg = lane & 15;
    int start = offs[wid], end = offs[wid + 1];
    float acc[8][4] = {};
    if (start < end)
        agg64_core((const unsigned short*)h, srcS, (const float4*)basisS, start, end, eg, fg, acc);
#pragma unroll
    for (int b = 0; b < 8; b++) {
#pragma unroll
        for (int c = 0; c < 4; c++) {
            float v = acc[b][c];
            v += __shfl_xor(v, 16, 64);
            v += __shfl_xor(v, 32, 64);
            acc[b][c] = v;
        }
    }
    // every lane holds full acc for its fg; contract with W3 (redundant x4 across eg)
    float o0 = 0.f, o1 = 0.f;
#pragma unroll
    for (int b = 0; b < 8; b++) {
        const float* w = W3 + (size_t)(b * 64 + fg * 4) * 2;
        float4 wa = *(const float4*)w;
        float4 wb = *(const float4*)(w + 4);
        o0 += acc[b][0] * wa.x + acc[b][1] * wa.z + acc[b][2] * wb.x + acc[b][3] * wb.z;
        o1 += acc[b][0] * wa.y + acc[b][1] * wa.w + acc[b][2] * wb.y + acc[b][3] * wb.w;
    }
#pragma unroll
    for (int m = 1; m < 16; m <<= 1) {
        o0 += __shfl_xor(o0, m, 64);
        o1 += __shfl_xor(o1, m, 64);
    }
    if (lane == 0) {
        out[(size_t)wid * 2 + 0] = o0 * (1.0f / 128.0f);
        out[(size_t)wid * 2 + 1] = o1 * (1.0f / 128.0f);
    }
}

// ---------------- agg F=16: lane = (eg 0..15, fg 0..3); 16 edges per wave-instruction ----------------

__global__ __launch_bounds__(256) void agg16_kernel(const __hip_bfloat16* __restrict__ h,
                                                    const int* __restrict__ srcS,
                                                    const float* __restrict__ basisS,
                                                    const int* __restrict__ offs,
                                                    __hip_bfloat16* __restrict__ A, int nN) {
    int wid = (blockIdx.x * 256 + threadIdx.x) >> 6;
    int lane = threadIdx.x & 63;
    if (wid >= nN) return;
    int eg = lane >> 2, fg = lane & 3;
    int start = offs[wid], end = offs[wid + 1];
    const unsigned short* hp = (const unsigned short*)h;
    const float4* bp = (const float4*)basisS;
    float acc[8][4] = {};
    for (int j = start; j < end; j += 16) {
        int e = j + eg;
        int q = min(e, end - 1);
        int s = srcS[q];
        u16x4 g = *(const u16x4*)(hp + (size_t)s * 16 + fg * 4);
        float4 c0 = bp[2 * q], c1 = bp[2 * q + 1];
        float hv[4];
        hv[0] = bf2f(g[0]); hv[1] = bf2f(g[1]); hv[2] = bf2f(g[2]); hv[3] = bf2f(g[3]);
        if (e >= end) { hv[0] = 0.f; hv[1] = 0.f; hv[2] = 0.f; hv[3] = 0.f; }
        float bas[8] = {c0.x, c0.y, c0.z, c0.w, c1.x, c1.y, c1.z, c1.w};
#pragma unroll
        for (int b = 0; b < 8; b++) {
#pragma unroll
            for (int c = 0; c < 4; c++) acc[b][c] += bas[b] * hv[c];
        }
    }
#pragma unroll
    for (int b = 0; b < 8; b++) {
#pragma unroll
        for (int c = 0; c < 4; c++) {
            float v = acc[b][c];
            v += __shfl_xor(v, 4, 64);
            v += __shfl_xor(v, 8, 64);
            v += __shfl_xor(v, 16, 64);
            v += __shfl_xor(v, 32, 64);
            acc[b][c] = v;
        }
    }
    if (eg == 0) {
        unsigned short* Ar = (unsigned short*)A + (size_t)wid * 128;
#pragma unroll
        for (int b = 0; b < 8; b++) {
            u16x4 p;
            p[0] = f2bf_bits(acc[b][0]); p[1] = f2bf_bits(acc[b][1]);
            p[2] = f2bf_bits(acc[b][2]); p[3] = f2bf_bits(acc[b][3]);
            *(u16x4*)(Ar + b * 16 + fg * 4) = p;
        }
    }
}

// ---------------- MFMA GEMM: Hout[n, 0..63] = relu(A[n, :K] @ Wt^T), bf16 out ----------------
// Frags (16x16x32 bf16): A/B lane mapping m/n = lane&15, k = (lane>>4)*8 + j.
// C/D: col = lane&15, row = (lane>>4)*4 + reg  [verified m89].

template <int K, bool RELU>
__global__ __launch_bounds__(256) void gemm_mfma_kernel(const __hip_bfloat16* __restrict__ A,
                                                        const __hip_bfloat16* __restrict__ Wt,
                                                        __hip_bfloat16* __restrict__ Hout, int nN) {
    int wave = threadIdx.x >> 6;
    int lane = threadIdx.x & 63;
    int m16 = lane & 15;
    int kg = lane >> 4;  // 0..3
    int arow = blockIdx.x * 64 + wave * 16 + m16;
    bool rowok = arow < nN;
    const short* Ap = (const short*)A;
    const short* Wp = (const short*)Wt;
    size_t abase = (size_t)arow * K + kg * 8;
    size_t wb0 = (size_t)(0 * 16 + m16) * K + kg * 8;
    size_t wb1 = (size_t)(1 * 16 + m16) * K + kg * 8;
    size_t wb2 = (size_t)(2 * 16 + m16) * K + kg * 8;
    size_t wb3 = (size_t)(3 * 16 + m16) * K + kg * 8;
    f32x4 acc0 = {0.f, 0.f, 0.f, 0.f};
    f32x4 acc1 = {0.f, 0.f, 0.f, 0.f};
    f32x4 acc2 = {0.f, 0.f, 0.f, 0.f};
    f32x4 acc3 = {0.f, 0.f, 0.f, 0.f};
#pragma unroll 4
    for (int kc = 0; kc < K; kc += 32) {
        bf16x8 af = {};
        if (rowok) af = *(const bf16x8*)(Ap + abase + kc);
        bf16x8 b0 = *(const bf16x8*)(Wp + wb0 + kc);
        bf16x8 b1 = *(const bf16x8*)(Wp + wb1 + kc);
        bf16x8 b2 = *(const bf16x8*)(Wp + wb2 + kc);
        bf16x8 b3 = *(const bf16x8*)(Wp + wb3 + kc);
        acc0 = __builtin_amdgcn_mfma_f32_16x16x32_bf16(af, b0, acc0, 0, 0, 0);
        acc1 = __builtin_amdgcn_mfma_f32_16x16x32_bf16(af, b1, acc1, 0, 0, 0);
        acc2 = __builtin_amdgcn_mfma_f32_16x16x32_bf16(af, b2, acc2, 0, 0, 0);
        acc3 = __builtin_amdgcn_mfma_f32_16x16x32_bf16(af, b3, acc3, 0, 0, 0);
    }
    int orow0 = blockIdx.x * 64 + wave * 16 + kg * 4;
#pragma unroll
    for (int r = 0; r < 4; r++) {
        int row = orow0 + r;
        if (row < nN) {
            float v0 = acc0[r], v1 = acc1[r], v2 = acc2[r], v3 = acc3[r];
            if (RELU) {
                v0 = fmaxf(v0, 0.0f); v1 = fmaxf(v1, 0.0f);
                v2 = fmaxf(v2, 0.0f); v3 = fmaxf(v3, 0.0f);
            }
            __hip_bfloat16* Hr = Hout + (size_t)row * 64;
            Hr[0 * 16 + m16] = __float2bfloat16(v0);
            Hr[1 * 16 + m16] = __float2bfloat16(v1);
            Hr[2 * 16 + m16] = __float2bfloat16(v2);
            Hr[3 * 16 + m16] = __float2bfloat16(v3);
        }
    }
}

// ---------------- launch ----------------

extern "C" void kernel_launch(void* const* d_in, const int* in_sizes, int n_in,
                              void* d_out, int out_size, void* d_ws, size_t ws_size,
                              hipStream_t stream) {
    const float* x  = (const float*)d_in[0];
    const int*   ei = (const int*)d_in[1];
    const float* el = (const float*)d_in[2];
    const float* W0 = (const float*)d_in[3];
    const float* W1 = (const float*)d_in[4];
    const float* W2 = (const float*)d_in[5];
    const float* W3 = (const float*)d_in[6];
    int nN = in_sizes[0] / 16;
    int E  = in_sizes[1] / 2;
    const int* src = ei;
    const int* dst = ei + E;

    char* ws = (char*)d_ws;
    size_t off = 0;
    auto alloc = [&](size_t bytes) -> void* {
        void* p = ws + off;
        off = (off + bytes + 255) & ~(size_t)255;
        return p;
    };
    int nsb = (nN + 255) / 256;  // scan blocks (must be <= 256)
    int*   cntcur = (int*)alloc((size_t)(nN + 1) * 4);
    int*   offs   = (int*)alloc((size_t)(nN + 1) * 4);
    int*   bsum   = (int*)alloc((size_t)nsb * 4);
    int*   boffs  = (int*)alloc((size_t)nsb * 4);
    int*   srcS   = (int*)alloc((size_t)E * 4);
    float* basisS = (float*)alloc((size_t)E * 8 * 4);
    __hip_bfloat16* Ab  = (__hip_bfloat16*)alloc((size_t)nN * 512 * 2);
    __hip_bfloat16* Wt0 = (__hip_bfloat16*)alloc((size_t)64 * 128 * 2);
    __hip_bfloat16* Wt1 = (__hip_bfloat16*)alloc((size_t)64 * 512 * 2);
    __hip_bfloat16* Wt2 = (__hip_bfloat16*)alloc((size_t)64 * 512 * 2);
    __hip_bfloat16* xb  = (__hip_bfloat16*)alloc((size_t)nN * 16 * 2);
    __hip_bfloat16* hA  = (__hip_bfloat16*)alloc((size_t)nN * 64 * 2);
    __hip_bfloat16* hB  = (__hip_bfloat16*)alloc((size_t)nN * 64 * 2);
    (void)ws_size;

    hipMemsetAsync(cntcur, 0, (size_t)nN * 4, stream);
    int eb = (E + 255) / 256;
    count_kernel<<<eb, 256, 0, stream>>>(dst, cntcur, E);
    scan_reduce_kernel<<<nsb, 256, 0, stream>>>(cntcur, bsum, nN);
    scan_top_kernel<<<1, 256, 0, stream>>>(bsum, boffs, nsb);
    scan_apply_kernel<<<nsb, 256, 0, stream>>>(cntcur, offs, boffs, nN, E);
    fill_kernel<<<eb, 256, 0, stream>>>(src, dst, el, cntcur, srcS, basisS, E);

    // preps (independent of binning; tiny)
    prep_w_kernel<<<(128 * 64 + 255) / 256, 256, 0, stream>>>(W0, Wt0, 128);
    prep_w_kernel<<<(512 * 64 + 255) / 256, 256, 0, stream>>>(W1, Wt1, 512);
    prep_w_kernel<<<(512 * 64 + 255) / 256, 256, 0, stream>>>(W2, Wt2, 512);
    prep_f2b_kernel<<<(nN * 16 + 255) / 256, 256, 0, stream>>>(x, xb, nN * 16);

    int nb = (nN + 3) / 4;    // wave-per-node kernels
    int gb = (nN + 63) / 64;  // gemm tiles

    // layer 0: in=16 -> 64
    agg16_kernel<<<nb, 256, 0, stream>>>(xb, srcS, basisS, offs, Ab, nN);
    gemm_mfma_kernel<128, true><<<gb, 256, 0, stream>>>(Ab, Wt0, hA, nN);
    // layer 1: 64 -> 64
    agg64_kernel<<<nb, 256, 0, stream>>>(hA, srcS, basisS, offs, Ab, nN);
    gemm_mfma_kernel<512, true><<<gb, 256, 0, stream>>>(Ab, Wt1, hB, nN);
    // layer 2: 64 -> 64
    agg64_kernel<<<nb, 256, 0, stream>>>(hB, srcS, basisS, offs, Ab, nN);
    gemm_mfma_kernel<512, true><<<gb, 256, 0, stream>>>(Ab, Wt2, hA, nN);
    // layer 3 fused: agg + [512x2] + scale
    agg_out_kernel<<<nb, 256, 0, stream>>>(hA, srcS, basisS, offs, W3, (float*)d_out, nN);
}